// Round 6
// baseline (686.523 us; speedup 1.0000x reference)
//
#include <hip/hip_runtime.h>
#include <math.h>

#define Bb 32
#define Pp 1024
#define Nn 1024

typedef unsigned short u16;
typedef __bf16 bf16x8 __attribute__((ext_vector_type(8)));
typedef float f32x4 __attribute__((ext_vector_type(4)));
typedef u16 us8 __attribute__((ext_vector_type(8)));

#define MFMA __builtin_amdgcn_mfma_f32_16x16x32_bf16

static constexpr float INV_SQRT_E = 0.08838834764831845f;  // 1/sqrt(128)

__device__ __forceinline__ bf16x8 asbf(us8 v) { return __builtin_bit_cast(bf16x8, v); }

// RTN split: x ~= hi + lo to ~2^-17 rel
__device__ __forceinline__ void bsplit(float x, u16& h, u16& l) {
  unsigned u = __float_as_uint(x);
  unsigned r = u + 0x7FFF + ((u >> 16) & 1);
  h = (u16)(r >> 16);
  float hf = __uint_as_float((unsigned)h << 16);
  float lof = x - hf;
  unsigned u2 = __float_as_uint(lof);
  unsigned r2 = u2 + 0x7FFF + ((u2 >> 16) & 1);
  l = (u16)(r2 >> 16);
}

// trunc split: x ~= hi + lo to ~2^-16 rel, cheap
__device__ __forceinline__ void tsplit(float x, u16& h, u16& l) {
  unsigned u = __float_as_uint(x);
  h = (u16)(u >> 16);
  float lof = x - __uint_as_float(u & 0xFFFF0000u);
  l = (u16)(__float_as_uint(lof) >> 16);
}

__device__ __forceinline__ float fast_tanh(float x) {
  float ax = fabsf(x);
  float t = __expf(-2.0f * ax);
  float r = (1.0f - t) / (1.0f + t);
  return copysignf(r, x);
}

// ---------------- K0: transposed split weight planes ----------------
__global__ __launch_bounds__(256) void prep_weights(
    const float* __restrict__ Wq1, const float* __restrict__ Wq2,
    const float* __restrict__ Wql, const float* __restrict__ Wk,
    const float* __restrict__ Wv, u16* __restrict__ wcat_hi, u16* __restrict__ wcat_lo,
    u16* __restrict__ wkv_hi, u16* __restrict__ wkv_lo) {
  int t = threadIdx.x;
  if (blockIdx.x == 0) {
    for (int i = t; i < 128 * 384; i += 256) {
      int c = i / 384, k = i % 384;
      float v = (k < 128) ? Wq1[k * 128 + c]
                          : (k < 256) ? Wq2[(k - 128) * 128 + c] : Wql[(k - 256) * 128 + c];
      u16 h, l;
      bsplit(v, h, l);
      wcat_hi[i] = h;
      wcat_lo[i] = l;
    }
  } else {
    for (int i = t; i < 256 * 128; i += 256) {
      int c = i >> 7, k = i & 127;
      float v = (c < 128) ? Wk[k * 128 + c] : Wv[k * 128 + (c - 128)];
      u16 h, l;
      bsplit(v, h, l);
      wkv_hi[i] = h;
      wkv_lo[i] = l;
    }
  }
}

// ---------------- K1: e_bias planes, packed A-frag order, into d_out ----------------
// tile i = p_flat>>4 (2048 tiles). Per-tile 64KB: [128 nc][16 pr][8 j] u16 hi, then lo.
__global__ __launch_bounds__(256) void bias_prep(
    const float* __restrict__ cdist, const float* __restrict__ ninf,
    u16* eb, const float* __restrict__ logs, const float* __restrict__ aal) {
  const float c1 = logs[0] * aal[0];
  int t0 = blockIdx.x * 256 + threadIdx.x;
  const int stride = 2048 * 256;
  for (int u = t0; u < 32 * 1024 * 128; u += stride) {
    long pf = u >> 7;  // b*1024+p
    int nb = u & 127;
    long off = pf * 1024 + nb * 8;
    float4 d0 = *(const float4*)&cdist[off];
    float4 d1 = *(const float4*)&cdist[off + 4];
    float4 f0 = *(const float4*)&ninf[off];
    float4 f1 = *(const float4*)&ninf[off + 4];
    float dv[8] = {d0.x, d0.y, d0.z, d0.w, d1.x, d1.y, d1.z, d1.w};
    float nv[8] = {f0.x, f0.y, f0.z, f0.w, f1.x, f1.y, f1.z, f1.w};
    us8 h8, l8;
#pragma unroll
    for (int j = 0; j < 8; ++j) {
      float ebv = __expf(fmaf(-c1, dv[j], nv[j]));
      u16 h, l;
      tsplit(ebv, h, l);
      h8[j] = h;
      l8[j] = l;
    }
    long widx = (pf >> 4) * 32768 + ((long)nb * 16 + (pf & 15)) * 8;
    *(us8*)&eb[widx] = h8;
    *(us8*)&eb[widx + 16384] = l8;
  }
}

// ---------------- K2: k/v GEMM (split MFMA) -> ekkP (B-frag packed) + nodesP ----------------
__global__ __launch_bounds__(256, 1) void kv_prep(
    const float* __restrict__ nodes, const u16* __restrict__ wkv_hi,
    const u16* __restrict__ wkv_lo, u16* __restrict__ ekkP_hi, u16* __restrict__ ekkP_lo,
    u16* __restrict__ nodesP_hi, u16* __restrict__ nodesP_lo) {
  __shared__ u16 a_hi[32 * 136], a_lo[32 * 136];
  __shared__ float kvbuf[32 * 264];
  const int t = threadIdx.x;
  const int xcd = blockIdx.x & 7, jj = blockIdx.x >> 3;
  const int b = xcd * 4 + (jj >> 5);
  const int n0 = (jj & 31) * 32;
  for (int i = t; i < 4096; i += 256) {
    int n = i >> 7, d = i & 127;
    float v = nodes[((long)(b * 1024 + n0 + n)) * 128 + d];
    u16 h, l;
    bsplit(v, h, l);
    a_hi[n * 136 + d] = h;
    a_lo[n * 136 + d] = l;
  }
  __syncthreads();
  const int lane = t & 63, w = t >> 6;
  const int lr = lane & 15, lg = lane >> 4;
  f32x4 acc0[2][4] = {}, acc1[2][4] = {};
#pragma unroll
  for (int ks = 0; ks < 4; ++ks) {
    us8 ah[2], al[2];
#pragma unroll
    for (int mt = 0; mt < 2; ++mt) {
      int ro = (lr + 16 * mt) * 136 + ks * 32 + lg * 8;
      ah[mt] = *(const us8*)&a_hi[ro];
      al[mt] = *(const us8*)&a_lo[ro];
    }
    us8 bh[4], bl[4];
#pragma unroll
    for (int cc = 0; cc < 4; ++cc) {
      long off = (long)((w * 4 + cc) * 16 + lr) * 128 + ks * 32 + lg * 8;
      bh[cc] = *(const us8*)&wkv_hi[off];
      bl[cc] = *(const us8*)&wkv_lo[off];
    }
#pragma unroll
    for (int mt = 0; mt < 2; ++mt)
#pragma unroll
      for (int cc = 0; cc < 4; ++cc) {
        acc0[mt][cc] = MFMA(asbf(ah[mt]), asbf(bh[cc]), acc0[mt][cc], 0, 0, 0);
        acc1[mt][cc] = MFMA(asbf(al[mt]), asbf(bh[cc]), acc1[mt][cc], 0, 0, 0);
        acc1[mt][cc] = MFMA(asbf(ah[mt]), asbf(bl[cc]), acc1[mt][cc], 0, 0, 0);
      }
  }
#pragma unroll
  for (int mt = 0; mt < 2; ++mt)
#pragma unroll
    for (int cc = 0; cc < 4; ++cc) {
      int c = (w * 4 + cc) * 16 + lr;
#pragma unroll
      for (int r = 0; r < 4; ++r)
        kvbuf[(lg * 4 + r + 16 * mt) * 264 + c] = acc0[mt][cc][r] + acc1[mt][cc][r];
    }
  __syncthreads();
  // ekkP output: idx = ((b*128 + n>>3)*256 + c)*8 + (n&7); threads map c-consecutive
#pragma unroll
  for (int jo = 0; jo < 4; ++jo) {
    int c = jo * 64 + (t & 63);
    int i4 = t >> 6;  // n-chunk
    int kcol = (c < 128) ? c : (c - 128);
    us8 h8, l8;
#pragma unroll
    for (int jq = 0; jq < 8; ++jq) {
      int n = i4 * 8 + jq;
      float kv = kvbuf[n * 264 + kcol];
      float ek = __expf(kv);
      float val = (c < 128) ? ek * kvbuf[n * 264 + c + 128] : ek;
      u16 h, l;
      bsplit(val, h, l);
      h8[jq] = h;
      l8[jq] = l;
    }
    long o = (((long)b * 128 + (n0 >> 3) + i4) * 256 + c) * 8;
    *(us8*)&ekkP_hi[o] = h8;
    *(us8*)&ekkP_lo[o] = l8;
  }
  {
    int pl = t >> 7, r = t & 127;
    int dgrp = r >> 3, nb = r & 7;
    const u16* src = pl ? a_lo : a_hi;
    u16* dst = pl ? nodesP_lo : nodesP_hi;
#pragma unroll
    for (int i = 0; i < 4; ++i) {
      int n = nb + 8 * i;
      us8 v = *(const us8*)&src[n * 136 + dgrp * 8];
      *(us8*)&dst[(((long)(b * 16 + dgrp)) * 1024 + n0 + n) * 8] = v;
    }
  }
}

// ---------------- main fused kernel: 32 p-rows per block, 512 threads ----------------
__global__ __launch_bounds__(512, 4) void main_kernel(
    const float* __restrict__ q1m, const float* __restrict__ q2m,
    const float* __restrict__ lnm, const float* __restrict__ loadv,
    const float* __restrict__ leftv, const float* __restrict__ cdist,
    const float* __restrict__ ninf, const float* __restrict__ Wql,
    const u16* __restrict__ wcat_hi, const u16* __restrict__ wcat_lo,
    const u16* __restrict__ ekkP_hi, const u16* __restrict__ ekkP_lo,
    const u16* __restrict__ nodesP_hi, const u16* __restrict__ nodesP_lo,
    const u16* eb, float* out, const float* __restrict__ logs,
    const float* __restrict__ aal, const float* __restrict__ pal) {
  __shared__ u16 aft_hi[32 * 136];
  __shared__ u16 aft_lo[32 * 136];
  __shared__ float sbuf[32 * 264];
  __shared__ float psum[32 * 4];
  __shared__ float invb[32];

  const int t = threadIdx.x;
  const int lane = t & 63, w = t >> 6;
  const int lr = lane & 15, lg = lane >> 4;
  const int rg = w & 1, cg = w >> 1;
  const int xcd = blockIdx.x & 7, j = blockIdx.x >> 3;
  const int b = xcd * 4 + (j >> 5);
  const int p0 = (j & 31) * 32;
  const long bp = (long)b * Pp + p0;
  const float ls = logs[0];
  const float c2 = ls * pal[0];

  const long arowg = bp + rg * 16 + lr;

  // ================= P1: q GEMM (K=384), A in-reg =================
  f32x4 qacc[2] = {};
#pragma unroll 2
  for (int s = 0; s < 12; ++s) {
    const float* __restrict__ src = (s < 4) ? q1m : (s < 8) ? q2m : lnm;
    long ao = arowg * 128 + (s & 3) * 32 + lg * 8;
    float4 a0 = *(const float4*)&src[ao];
    float4 a1 = *(const float4*)&src[ao + 4];
    float av[8] = {a0.x, a0.y, a0.z, a0.w, a1.x, a1.y, a1.z, a1.w};
    us8 ah, al;
#pragma unroll
    for (int jq = 0; jq < 8; ++jq) {
      u16 hh, ll;
      tsplit(av[jq], hh, ll);
      ah[jq] = hh;
      al[jq] = ll;
    }
#pragma unroll
    for (int cf = 0; cf < 2; ++cf) {
      int c = cg * 32 + cf * 16 + lr;
      us8 bh = *(const us8*)&wcat_hi[c * 384 + s * 32 + lg * 8];
      us8 bl = *(const us8*)&wcat_lo[c * 384 + s * 32 + lg * 8];
      qacc[cf] = MFMA(asbf(ah), asbf(bh), qacc[cf], 0, 0, 0);
      qacc[cf] = MFMA(asbf(al), asbf(bh), qacc[cf], 0, 0, 0);
      qacc[cf] = MFMA(asbf(ah), asbf(bl), qacc[cf], 0, 0, 0);
    }
  }
  float sigv[2][4];
#pragma unroll
  for (int cf = 0; cf < 2; ++cf) {
    int c = cg * 32 + cf * 16 + lr;
    float wl1 = Wql[128 * 128 + c], wl2 = Wql[129 * 128 + c];
#pragma unroll
    for (int r = 0; r < 4; ++r) {
      int row = rg * 16 + lg * 4 + r;
      float qv = qacc[cf][r] + loadv[bp + row] * wl1 + leftv[bp + row] * wl2;
      sigv[cf][r] = 1.0f / (1.0f + __expf(-qv));
    }
  }

  // ================= P2: [num|den] = e_bias @ ekk, pure streaming GEMM ==========
  f32x4 acc2[4] = {};
  int ccol[4];
#pragma unroll
  for (int cf = 0; cf < 4; ++cf)
    ccol[cf] = ((cf < 2) ? (cg * 32 + cf * 16) : (128 + cg * 32 + (cf - 2) * 16)) + lr;
  const long tileA = ((long)(b * 64) + (p0 >> 4) + rg) * 32768;  // u16 idx
  const long bB = (long)b * 128;
#pragma unroll 4
  for (int s = 0; s < 32; ++s) {
    int nc = s * 4 + lg;
    long aoff = tileA + (nc * 16 + lr) * 8;
    us8 ah = *(const us8*)&eb[aoff];
    us8 al = *(const us8*)&eb[aoff + 16384];
    long bnc = (bB + nc) * 2048;
#pragma unroll
    for (int cf = 0; cf < 4; ++cf) {
      us8 bh = *(const us8*)&ekkP_hi[bnc + ccol[cf] * 8];
      us8 bl = *(const us8*)&ekkP_lo[bnc + ccol[cf] * 8];
      acc2[cf] = MFMA(asbf(ah), asbf(bh), acc2[cf], 0, 0, 0);
      acc2[cf] = MFMA(asbf(al), asbf(bh), acc2[cf], 0, 0, 0);
      acc2[cf] = MFMA(asbf(ah), asbf(bl), acc2[cf], 0, 0, 0);
    }
  }

  // ================= P3: AFT lane-local -> split LDS =================
#pragma unroll
  for (int cf = 0; cf < 2; ++cf) {
#pragma unroll
    for (int r = 0; r < 4; ++r) {
      float aftv = sigv[cf][r] * (acc2[cf][r] / (acc2[cf + 2][r] + 1e-20f));
      u16 h, l;
      bsplit(aftv, h, l);
      int row = rg * 16 + lg * 4 + r;
      int c = cg * 32 + cf * 16 + lr;
      aft_hi[row * 136 + c] = h;
      aft_lo[row * 136 + c] = l;
    }
  }
  __syncthreads();

  // ================= P4: score = AFT @ nodes^T =================
  f32x4 sacc[16] = {};
#pragma unroll
  for (int ks = 0; ks < 4; ++ks) {
    us8 ah = *(const us8*)&aft_hi[(rg * 16 + lr) * 136 + ks * 32 + lg * 8];
    us8 al = *(const us8*)&aft_lo[(rg * 16 + lr) * 136 + ks * 32 + lg * 8];
    long nb = ((long)(b * 16 + ks * 4 + lg)) * 1024;
#pragma unroll
    for (int cf = 0; cf < 16; ++cf) {
      long o = (nb + cg * 256 + cf * 16 + lr) * 8;
      us8 bh = *(const us8*)&nodesP_hi[o];
      us8 bl = *(const us8*)&nodesP_lo[o];
      sacc[cf] = MFMA(asbf(ah), asbf(bh), sacc[cf], 0, 0, 0);
      sacc[cf] = MFMA(asbf(al), asbf(bh), sacc[cf], 0, 0, 0);
      sacc[cf] = MFMA(asbf(ah), asbf(bl), sacc[cf], 0, 0, 0);
    }
  }

  // ================= P5a: scale + dist + tanh-clip + exp =================
  float rs[4] = {};
#pragma unroll
  for (int cf = 0; cf < 16; ++cf) {
    int n = cg * 256 + cf * 16 + lr;
#pragma unroll
    for (int r = 0; r < 4; ++r) {
      int row = rg * 16 + lg * 4 + r;
      long off = (bp + row) * (long)Nn + n;
      float sv = fmaf(sacc[cf][r], INV_SQRT_E, -c2 * cdist[off]);
      float e = __expf(10.0f * fast_tanh(sv) + ninf[off]);
      sacc[cf][r] = e;
      rs[r] += e;
    }
  }
#pragma unroll
  for (int r = 0; r < 4; ++r) {
    float v = rs[r];
    v += __shfl_xor(v, 1);
    v += __shfl_xor(v, 2);
    v += __shfl_xor(v, 4);
    v += __shfl_xor(v, 8);
    rs[r] = v;
  }
  if (lr == 0) {
#pragma unroll
    for (int r = 0; r < 4; ++r) psum[(rg * 16 + lg * 4 + r) * 4 + cg] = rs[r];
  }
  __syncthreads();
  if (t < 32)
    invb[t] = 1.0f / (psum[t * 4] + psum[t * 4 + 1] + psum[t * 4 + 2] + psum[t * 4 + 3]);
  __syncthreads();

  // ================= P5c: LDS-staged, fully-coalesced stores =================
#pragma unroll 1
  for (int c = 0; c < 4; ++c) {
    if (cg == c) {
#pragma unroll
      for (int cf = 0; cf < 16; ++cf)
#pragma unroll
        for (int r = 0; r < 4; ++r) {
          int row = rg * 16 + lg * 4 + r;
          sbuf[row * 264 + cf * 16 + lr] = sacc[cf][r] * invb[row];
        }
    }
    __syncthreads();
    {
      int row = t >> 4, cq = t & 15;
      long ro = (bp + row) * (long)Nn + c * 256 + cq * 16;
#pragma unroll
      for (int i = 0; i < 4; ++i)
        *(float4*)&out[ro + i * 4] = *(const float4*)&sbuf[row * 264 + cq * 16 + i * 4];
    }
    __syncthreads();
  }
}

extern "C" void kernel_launch(void* const* d_in, const int* in_sizes, int n_in,
                              void* d_out, int out_size, void* d_ws, size_t ws_size,
                              hipStream_t stream) {
  const float* nodes = (const float*)d_in[0];
  const float* q1m = (const float*)d_in[1];
  const float* q2m = (const float*)d_in[2];
  const float* lnm = (const float*)d_in[3];
  const float* loadv = (const float*)d_in[4];
  const float* leftv = (const float*)d_in[5];
  const float* cdist = (const float*)d_in[6];
  const float* logs = (const float*)d_in[7];
  const float* ninf = (const float*)d_in[8];
  const float* Wq1 = (const float*)d_in[9];
  const float* Wq2 = (const float*)d_in[10];
  const float* Wql = (const float*)d_in[11];
  const float* Wk = (const float*)d_in[12];
  const float* Wv = (const float*)d_in[13];
  const float* aalpha = (const float*)d_in[14];
  const float* palpha = (const float*)d_in[15];

  char* ws = (char*)d_ws;
  u16* ekkP_hi = (u16*)ws;                            // 16 MB
  u16* ekkP_lo = (u16*)(ws + (16u << 20));            // 16 MB
  u16* nodesP_hi = (u16*)(ws + (32u << 20));          // 8 MB
  u16* nodesP_lo = (u16*)(ws + (40u << 20));          // 8 MB
  u16* wcat_hi = (u16*)(ws + (48u << 20));
  u16* wcat_lo = wcat_hi + 128 * 384;
  u16* wkv_hi = wcat_lo + 128 * 384;
  u16* wkv_lo = wkv_hi + 256 * 128;
  u16* eb = (u16*)d_out;  // e_bias planes live in d_out until overwritten by P5c

  prep_weights<<<2, 256, 0, stream>>>(Wq1, Wq2, Wql, Wk, Wv, wcat_hi, wcat_lo, wkv_hi, wkv_lo);
  kv_prep<<<Bb * Nn / 32, 256, 0, stream>>>(nodes, wkv_hi, wkv_lo, ekkP_hi, ekkP_lo,
                                            nodesP_hi, nodesP_lo);
  bias_prep<<<2048, 256, 0, stream>>>(cdist, ninf, eb, logs, aalpha);
  main_kernel<<<Bb * Pp / 32, 512, 0, stream>>>(
      q1m, q2m, lnm, loadv, leftv, cdist, ninf, Wql, wcat_hi, wcat_lo, ekkP_hi, ekkP_lo,
      nodesP_hi, nodesP_lo, eb, (float*)d_out, logs, aalpha, palpha);
}

// Round 7
// 527.682 us; speedup vs baseline: 1.3010x; 1.3010x over previous
//
#include <hip/hip_runtime.h>
#include <math.h>

#define Bb 32
#define Pp 1024
#define Nn 1024

typedef unsigned short u16;
typedef __bf16 bf16x8 __attribute__((ext_vector_type(8)));
typedef float f32x4 __attribute__((ext_vector_type(4)));
typedef u16 us8 __attribute__((ext_vector_type(8)));

#define MFMA __builtin_amdgcn_mfma_f32_16x16x32_bf16

static constexpr float INV_SQRT_E = 0.08838834764831845f;  // 1/sqrt(128)

__device__ __forceinline__ bf16x8 asbf(us8 v) { return __builtin_bit_cast(bf16x8, v); }

// RTN split: x ~= hi + lo to ~2^-17 rel
__device__ __forceinline__ void bsplit(float x, u16& h, u16& l) {
  unsigned u = __float_as_uint(x);
  unsigned r = u + 0x7FFF + ((u >> 16) & 1);
  h = (u16)(r >> 16);
  float hf = __uint_as_float((unsigned)h << 16);
  float lof = x - hf;
  unsigned u2 = __float_as_uint(lof);
  unsigned r2 = u2 + 0x7FFF + ((u2 >> 16) & 1);
  l = (u16)(r2 >> 16);
}

// trunc split: x ~= hi + lo to ~2^-16 rel, cheap
__device__ __forceinline__ void tsplit(float x, u16& h, u16& l) {
  unsigned u = __float_as_uint(x);
  h = (u16)(u >> 16);
  float lof = x - __uint_as_float(u & 0xFFFF0000u);
  l = (u16)(__float_as_uint(lof) >> 16);
}

__device__ __forceinline__ float fast_tanh(float x) {
  float ax = fabsf(x);
  float t = __expf(-2.0f * ax);
  float r = (1.0f - t) / (1.0f + t);
  return copysignf(r, x);
}

// ---------------- K0: transposed split weight planes ----------------
__global__ __launch_bounds__(256) void prep_weights(
    const float* __restrict__ Wq1, const float* __restrict__ Wq2,
    const float* __restrict__ Wql, const float* __restrict__ Wk,
    const float* __restrict__ Wv, u16* __restrict__ wcat_hi, u16* __restrict__ wcat_lo,
    u16* __restrict__ wkv_hi, u16* __restrict__ wkv_lo) {
  int t = threadIdx.x;
  if (blockIdx.x == 0) {
    for (int i = t; i < 128 * 384; i += 256) {
      int c = i / 384, k = i % 384;
      float v = (k < 128) ? Wq1[k * 128 + c]
                          : (k < 256) ? Wq2[(k - 128) * 128 + c] : Wql[(k - 256) * 128 + c];
      u16 h, l;
      bsplit(v, h, l);
      wcat_hi[i] = h;
      wcat_lo[i] = l;
    }
  } else {
    for (int i = t; i < 256 * 128; i += 256) {
      int c = i >> 7, k = i & 127;
      float v = (c < 128) ? Wk[k * 128 + c] : Wv[k * 128 + (c - 128)];
      u16 h, l;
      bsplit(v, h, l);
      wkv_hi[i] = h;
      wkv_lo[i] = l;
    }
  }
}

// ---------------- K1: k/v GEMM -> ekkP (B-frag packed, [b][nch][256c][8]) + nodesP ----------------
__global__ __launch_bounds__(256, 1) void kv_prep(
    const float* __restrict__ nodes, const u16* __restrict__ wkv_hi,
    const u16* __restrict__ wkv_lo, u16* __restrict__ ekkP_hi, u16* __restrict__ ekkP_lo,
    u16* __restrict__ nodesP_hi, u16* __restrict__ nodesP_lo) {
  __shared__ u16 a_hi[32 * 136], a_lo[32 * 136];
  __shared__ float kvbuf[32 * 264];
  const int t = threadIdx.x;
  const int xcd = blockIdx.x & 7, jj = blockIdx.x >> 3;
  const int b = xcd * 4 + (jj >> 5);
  const int n0 = (jj & 31) * 32;
  for (int i = t; i < 4096; i += 256) {
    int n = i >> 7, d = i & 127;
    float v = nodes[((long)(b * 1024 + n0 + n)) * 128 + d];
    u16 h, l;
    bsplit(v, h, l);
    a_hi[n * 136 + d] = h;
    a_lo[n * 136 + d] = l;
  }
  __syncthreads();
  const int lane = t & 63, w = t >> 6;
  const int lr = lane & 15, lg = lane >> 4;
  f32x4 acc0[2][4] = {}, acc1[2][4] = {};
#pragma unroll
  for (int ks = 0; ks < 4; ++ks) {
    us8 ah[2], al[2];
#pragma unroll
    for (int mt = 0; mt < 2; ++mt) {
      int ro = (lr + 16 * mt) * 136 + ks * 32 + lg * 8;
      ah[mt] = *(const us8*)&a_hi[ro];
      al[mt] = *(const us8*)&a_lo[ro];
    }
    us8 bh[4], bl[4];
#pragma unroll
    for (int cc = 0; cc < 4; ++cc) {
      long off = (long)((w * 4 + cc) * 16 + lr) * 128 + ks * 32 + lg * 8;
      bh[cc] = *(const us8*)&wkv_hi[off];
      bl[cc] = *(const us8*)&wkv_lo[off];
    }
#pragma unroll
    for (int mt = 0; mt < 2; ++mt)
#pragma unroll
      for (int cc = 0; cc < 4; ++cc) {
        acc0[mt][cc] = MFMA(asbf(ah[mt]), asbf(bh[cc]), acc0[mt][cc], 0, 0, 0);
        acc1[mt][cc] = MFMA(asbf(al[mt]), asbf(bh[cc]), acc1[mt][cc], 0, 0, 0);
        acc1[mt][cc] = MFMA(asbf(ah[mt]), asbf(bl[cc]), acc1[mt][cc], 0, 0, 0);
      }
  }
#pragma unroll
  for (int mt = 0; mt < 2; ++mt)
#pragma unroll
    for (int cc = 0; cc < 4; ++cc) {
      int c = (w * 4 + cc) * 16 + lr;
#pragma unroll
      for (int r = 0; r < 4; ++r)
        kvbuf[(lg * 4 + r + 16 * mt) * 264 + c] = acc0[mt][cc][r] + acc1[mt][cc][r];
    }
  __syncthreads();
#pragma unroll
  for (int jo = 0; jo < 4; ++jo) {
    int c = jo * 64 + (t & 63);
    int i4 = t >> 6;
    int kcol = (c < 128) ? c : (c - 128);
    us8 h8, l8;
#pragma unroll
    for (int jq = 0; jq < 8; ++jq) {
      int n = i4 * 8 + jq;
      float kv = kvbuf[n * 264 + kcol];
      float ek = __expf(kv);
      float val = (c < 128) ? ek * kvbuf[n * 264 + c + 128] : ek;
      u16 h, l;
      bsplit(val, h, l);
      h8[jq] = h;
      l8[jq] = l;
    }
    long o = (((long)b * 128 + (n0 >> 3) + i4) * 256 + c) * 8;
    *(us8*)&ekkP_hi[o] = h8;
    *(us8*)&ekkP_lo[o] = l8;
  }
  {
    int pl = t >> 7, r = t & 127;
    int dgrp = r >> 3, nb = r & 7;
    const u16* src = pl ? a_lo : a_hi;
    u16* dst = pl ? nodesP_lo : nodesP_hi;
#pragma unroll
    for (int i = 0; i < 4; ++i) {
      int n = nb + 8 * i;
      us8 v = *(const us8*)&src[n * 136 + dgrp * 8];
      *(us8*)&dst[(((long)(b * 16 + dgrp)) * 1024 + n0 + n) * 8] = v;
    }
  }
}

// ---------------- K2: e_bias planes, A-frag packed per 16-row tile ----------------
// eb[tile][128 nc][16 pr][8 j]; tile = flat_row>>4; hi/lo separate planes.
__global__ __launch_bounds__(256) void bias_prep(
    const float* __restrict__ cdist, const float* __restrict__ ninf,
    u16* __restrict__ eb_hi, u16* __restrict__ eb_lo,
    const float* __restrict__ logs, const float* __restrict__ aal) {
  const float c1 = logs[0] * aal[0];
  const int tile = blockIdx.x;
  const long prow = (long)tile * 16;
  const int t = threadIdx.x;
#pragma unroll 2
  for (int it = 0; it < 8; ++it) {
    int item = t + it * 256;  // nc*16 + pr
    int nc = item >> 4, pr = item & 15;
    long off = (prow + pr) * 1024 + nc * 8;
    float4 d0 = *(const float4*)&cdist[off];
    float4 d1 = *(const float4*)&cdist[off + 4];
    float4 f0 = *(const float4*)&ninf[off];
    float4 f1 = *(const float4*)&ninf[off + 4];
    float dv[8] = {d0.x, d0.y, d0.z, d0.w, d1.x, d1.y, d1.z, d1.w};
    float nv[8] = {f0.x, f0.y, f0.z, f0.w, f1.x, f1.y, f1.z, f1.w};
    us8 h8, l8;
#pragma unroll
    for (int jq = 0; jq < 8; ++jq) {
      float ebv = __expf(fmaf(-c1, dv[jq], nv[jq]));
      u16 h, l;
      tsplit(ebv, h, l);
      h8[jq] = h;
      l8[jq] = l;
    }
    long widx = (long)tile * 16384 + (long)item * 8;
    *(us8*)&eb_hi[widx] = h8;
    *(us8*)&eb_lo[widx] = l8;
  }
}

// ---------------- K3: nd GEMM: [num|den] = e_bias @ ekk, 128x128xBK32 LDS-tiled ----------------
// 256 thr / 4 waves, each wave 64x64 (4x4 16x16 frags). Reg-staged T14 pipeline.
__global__ __launch_bounds__(256, 3) void nd_gemm(
    const u16* __restrict__ eb_hi, const u16* __restrict__ eb_lo,
    const u16* __restrict__ ekkP_hi, const u16* __restrict__ ekkP_lo,
    float* __restrict__ nd) {
  __shared__ u16 Albs[8192];  // [ptile8][pl2][nc4][pr16][8]
  __shared__ u16 Blbs[8192];  // [nc4][pl2][ch2][c64][8]
  const int t = threadIdx.x;
  const int lane = t & 63, w = t >> 6;
  const int lr = lane & 15, lg = lane >> 4;
  const int wr = w >> 1, wc = w & 1;
  const int xcd = blockIdx.x & 7, j = blockIdx.x >> 3;
  const int b = xcd * 4 + (j >> 4);
  const int mt8 = (j >> 1) & 7;
  const int nh = j & 1;
  const int tile0 = b * 64 + mt8 * 8;
  const long bp = (long)b * Pp + mt8 * 128;
  const int c0 = nh * 128;

  us8 st[8];
  auto load_step = [&](int s) {
#pragma unroll
    for (int i = 0; i < 8; ++i) {
      int cidx = w * 8 + i;
      const u16* src;
      if (cidx < 16) {
        int ptile = cidx >> 1, pl = cidx & 1;
        const u16* ebP = pl ? eb_lo : eb_hi;
        src = ebP + ((long)(tile0 + ptile) * 16384) + s * 512 + lane * 8;
      } else {
        int lc = cidx - 16;
        int nc = lc >> 2, pl = (lc >> 1) & 1, ch = lc & 1;
        const u16* bP = pl ? ekkP_lo : ekkP_hi;
        src = bP + ((long)(b * 128 + s * 4 + nc) * 2048) + c0 * 8 + ch * 512 + lane * 8;
      }
      st[i] = *(const us8*)src;
    }
  };
  auto write_step = [&]() {
#pragma unroll
    for (int i = 0; i < 8; ++i) {
      int cidx = w * 8 + i;
      u16* dst = (cidx < 16) ? &Albs[cidx * 512 + lane * 8]
                             : &Blbs[(cidx - 16) * 512 + lane * 8];
      *(us8*)dst = st[i];
    }
  };

  f32x4 acc[4][4] = {};
  load_step(0);
  for (int s = 0; s < 32; ++s) {
    __syncthreads();  // prior compute done reading LDS
    write_step();
    if (s < 31) load_step(s + 1);  // in flight across the compute phase
    __syncthreads();  // staged data visible
    us8 ah[4], al[4];
#pragma unroll
    for (int mt = 0; mt < 4; ++mt) {
      int pt2 = (wr * 4 + mt) * 2;
      ah[mt] = *(const us8*)&Albs[pt2 * 512 + lg * 128 + lr * 8];
      al[mt] = *(const us8*)&Albs[(pt2 + 1) * 512 + lg * 128 + lr * 8];
    }
#pragma unroll
    for (int ct = 0; ct < 4; ++ct) {
      int cc = wc * 64 + ct * 16 + lr;
      us8 bh = *(const us8*)&Blbs[(lg * 4 + (cc >> 6)) * 512 + (cc & 63) * 8];
      us8 bl = *(const us8*)&Blbs[(lg * 4 + 2 + (cc >> 6)) * 512 + (cc & 63) * 8];
#pragma unroll
      for (int mt = 0; mt < 4; ++mt) {
        acc[mt][ct] = MFMA(asbf(ah[mt]), asbf(bh), acc[mt][ct], 0, 0, 0);
        acc[mt][ct] = MFMA(asbf(al[mt]), asbf(bh), acc[mt][ct], 0, 0, 0);
        acc[mt][ct] = MFMA(asbf(ah[mt]), asbf(bl), acc[mt][ct], 0, 0, 0);
      }
    }
  }
#pragma unroll
  for (int mt = 0; mt < 4; ++mt)
#pragma unroll
    for (int ct = 0; ct < 4; ++ct) {
      int ccol = c0 + wc * 64 + ct * 16 + lr;
#pragma unroll
      for (int r = 0; r < 4; ++r) {
        int row = wr * 64 + mt * 16 + lg * 4 + r;
        nd[(bp + row) * 256 + ccol] = acc[mt][ct][r];
      }
    }
}

// ---------------- K4: q GEMM + sigmoid + AFT -> split aftP planes (A-frag packed) ----------------
__global__ __launch_bounds__(256) void aft_prep(
    const float* __restrict__ q1m, const float* __restrict__ q2m,
    const float* __restrict__ lnm, const float* __restrict__ loadv,
    const float* __restrict__ leftv, const float* __restrict__ Wql,
    const u16* __restrict__ wcat_hi, const u16* __restrict__ wcat_lo,
    const float* __restrict__ nd, u16* __restrict__ aftP_hi,
    u16* __restrict__ aftP_lo) {
  __shared__ float qs[16 * 132];
  const int t = threadIdx.x;
  const int lane = t & 63, w = t >> 6;
  const int lr = lane & 15, lg = lane >> 4;
  const int tile = blockIdx.x;
  const long p0 = (long)tile * 16;
  const long arow = p0 + lr;
  f32x4 qacc[2] = {};
#pragma unroll 2
  for (int s = 0; s < 12; ++s) {
    const float* __restrict__ src = (s < 4) ? q1m : (s < 8) ? q2m : lnm;
    long ao = arow * 128 + (s & 3) * 32 + lg * 8;
    float4 a0 = *(const float4*)&src[ao];
    float4 a1 = *(const float4*)&src[ao + 4];
    float av[8] = {a0.x, a0.y, a0.z, a0.w, a1.x, a1.y, a1.z, a1.w};
    us8 ah, al;
#pragma unroll
    for (int jq = 0; jq < 8; ++jq) {
      u16 hh, ll;
      tsplit(av[jq], hh, ll);
      ah[jq] = hh;
      al[jq] = ll;
    }
#pragma unroll
    for (int cf = 0; cf < 2; ++cf) {
      int c = w * 32 + cf * 16 + lr;
      us8 bh = *(const us8*)&wcat_hi[c * 384 + s * 32 + lg * 8];
      us8 bl = *(const us8*)&wcat_lo[c * 384 + s * 32 + lg * 8];
      qacc[cf] = MFMA(asbf(ah), asbf(bh), qacc[cf], 0, 0, 0);
      qacc[cf] = MFMA(asbf(al), asbf(bh), qacc[cf], 0, 0, 0);
      qacc[cf] = MFMA(asbf(ah), asbf(bl), qacc[cf], 0, 0, 0);
    }
  }
#pragma unroll
  for (int cf = 0; cf < 2; ++cf) {
    int c = w * 32 + cf * 16 + lr;
    float wl1 = Wql[128 * 128 + c], wl2 = Wql[129 * 128 + c];
#pragma unroll
    for (int r = 0; r < 4; ++r) {
      int row = lg * 4 + r;
      float qv = qacc[cf][r] + loadv[p0 + row] * wl1 + leftv[p0 + row] * wl2;
      qs[row * 132 + c] = 1.0f / (1.0f + __expf(-qv));
    }
  }
  __syncthreads();
  {
    int row = t >> 4, nc = t & 15;
    long ndb = (p0 + row) * 256 + nc * 8;
    float4 n0 = *(const float4*)&nd[ndb];
    float4 n1 = *(const float4*)&nd[ndb + 4];
    float4 e0 = *(const float4*)&nd[ndb + 128];
    float4 e1 = *(const float4*)&nd[ndb + 132];
    float num[8] = {n0.x, n0.y, n0.z, n0.w, n1.x, n1.y, n1.z, n1.w};
    float den[8] = {e0.x, e0.y, e0.z, e0.w, e1.x, e1.y, e1.z, e1.w};
    us8 h8, l8;
#pragma unroll
    for (int jq = 0; jq < 8; ++jq) {
      float sig = qs[row * 132 + nc * 8 + jq];
      float aftv = sig * (num[jq] / (den[jq] + 1e-20f));
      u16 h, l;
      bsplit(aftv, h, l);
      h8[jq] = h;
      l8[jq] = l;
    }
    long widx = (long)tile * 2048 + ((long)(nc * 16 + row)) * 8;
    *(us8*)&aftP_hi[widx] = h8;
    *(us8*)&aftP_lo[widx] = l8;
  }
}

// ---------------- K5: score GEMM + tanh-clip softmax, 32 rows/block ----------------
__global__ __launch_bounds__(512, 4) void score_softmax(
    const float* __restrict__ cdist, const float* __restrict__ ninf,
    const u16* __restrict__ aftP_hi, const u16* __restrict__ aftP_lo,
    const u16* __restrict__ nodesP_hi, const u16* __restrict__ nodesP_lo,
    float* __restrict__ out, const float* __restrict__ logs,
    const float* __restrict__ pal) {
  __shared__ float sbuf[32 * 264];
  __shared__ float psum[32 * 4];
  __shared__ float invb[32];
  const int t = threadIdx.x;
  const int lane = t & 63, w = t >> 6;
  const int lr = lane & 15, lg = lane >> 4;
  const int rg = w & 1, cg = w >> 1;
  const int xcd = blockIdx.x & 7, j = blockIdx.x >> 3;
  const int b = xcd * 4 + (j >> 5);
  const int p0 = (j & 31) * 32;
  const long bp = (long)b * Pp + p0;
  const float c2 = logs[0] * pal[0];
  const int tileb = b * 64 + (p0 >> 4);

  f32x4 sacc[16] = {};
#pragma unroll
  for (int ks = 0; ks < 4; ++ks) {
    long aoff = (long)(tileb + rg) * 2048 + ((long)((ks * 4 + lg) * 16 + lr)) * 8;
    us8 ah = *(const us8*)&aftP_hi[aoff];
    us8 al = *(const us8*)&aftP_lo[aoff];
    long nb = ((long)(b * 16 + ks * 4 + lg)) * 1024;
#pragma unroll
    for (int cf = 0; cf < 16; ++cf) {
      long o = (nb + cg * 256 + cf * 16 + lr) * 8;
      us8 bh = *(const us8*)&nodesP_hi[o];
      us8 bl = *(const us8*)&nodesP_lo[o];
      sacc[cf] = MFMA(asbf(ah), asbf(bh), sacc[cf], 0, 0, 0);
      sacc[cf] = MFMA(asbf(al), asbf(bh), sacc[cf], 0, 0, 0);
      sacc[cf] = MFMA(asbf(ah), asbf(bl), sacc[cf], 0, 0, 0);
    }
  }

  float rs[4] = {};
#pragma unroll
  for (int cf = 0; cf < 16; ++cf) {
    int n = cg * 256 + cf * 16 + lr;
#pragma unroll
    for (int r = 0; r < 4; ++r) {
      int row = rg * 16 + lg * 4 + r;
      long off = (bp + row) * (long)Nn + n;
      float sv = fmaf(sacc[cf][r], INV_SQRT_E, -c2 * cdist[off]);
      float e = __expf(10.0f * fast_tanh(sv) + ninf[off]);
      sacc[cf][r] = e;
      rs[r] += e;
    }
  }
#pragma unroll
  for (int r = 0; r < 4; ++r) {
    float v = rs[r];
    v += __shfl_xor(v, 1);
    v += __shfl_xor(v, 2);
    v += __shfl_xor(v, 4);
    v += __shfl_xor(v, 8);
    rs[r] = v;
  }
  if (lr == 0) {
#pragma unroll
    for (int r = 0; r < 4; ++r) psum[(rg * 16 + lg * 4 + r) * 4 + cg] = rs[r];
  }
  __syncthreads();
  if (t < 32)
    invb[t] = 1.0f / (psum[t * 4] + psum[t * 4 + 1] + psum[t * 4 + 2] + psum[t * 4 + 3]);
  __syncthreads();

#pragma unroll 1
  for (int c = 0; c < 4; ++c) {
    if (cg == c) {
#pragma unroll
      for (int cf = 0; cf < 16; ++cf)
#pragma unroll
        for (int r = 0; r < 4; ++r) {
          int row = rg * 16 + lg * 4 + r;
          sbuf[row * 264 + cf * 16 + lr] = sacc[cf][r] * invb[row];
        }
    }
    __syncthreads();
    {
      int row = t >> 4, cq = t & 15;
      long ro = (bp + row) * (long)Nn + c * 256 + cq * 16;
#pragma unroll
      for (int i = 0; i < 4; ++i)
        *(float4*)&out[ro + i * 4] = *(const float4*)&sbuf[row * 264 + cq * 16 + i * 4];
    }
    __syncthreads();
  }
}

extern "C" void kernel_launch(void* const* d_in, const int* in_sizes, int n_in,
                              void* d_out, int out_size, void* d_ws, size_t ws_size,
                              hipStream_t stream) {
  const float* nodes = (const float*)d_in[0];
  const float* q1m = (const float*)d_in[1];
  const float* q2m = (const float*)d_in[2];
  const float* lnm = (const float*)d_in[3];
  const float* loadv = (const float*)d_in[4];
  const float* leftv = (const float*)d_in[5];
  const float* cdist = (const float*)d_in[6];
  const float* logs = (const float*)d_in[7];
  const float* ninf = (const float*)d_in[8];
  const float* Wq1 = (const float*)d_in[9];
  const float* Wq2 = (const float*)d_in[10];
  const float* Wql = (const float*)d_in[11];
  const float* Wk = (const float*)d_in[12];
  const float* Wv = (const float*)d_in[13];
  const float* aalpha = (const float*)d_in[14];
  const float* palpha = (const float*)d_in[15];

  char* ws = (char*)d_ws;
  u16* ekkP_hi = (u16*)ws;                      // 16 MB
  u16* ekkP_lo = (u16*)(ws + (16ul << 20));     // 16 MB
  u16* nodesP_hi = (u16*)(ws + (32ul << 20));   // 8 MB
  u16* nodesP_lo = (u16*)(ws + (40ul << 20));   // 8 MB
  float* nd = (float*)(ws + (48ul << 20));      // 32 MB f32 [b][p][256]
  u16* aftP_hi = (u16*)(ws + (80ul << 20));     // 8 MB
  u16* aftP_lo = (u16*)(ws + (88ul << 20));     // 8 MB
  u16* wcat_hi = (u16*)(ws + (96ul << 20));
  u16* wcat_lo = wcat_hi + 128 * 384;
  u16* wkv_hi = wcat_lo + 128 * 384;
  u16* wkv_lo = wkv_hi + 256 * 128;
  // e_bias planes live in d_out until score_softmax overwrites it
  u16* eb_hi = (u16*)d_out;
  u16* eb_lo = eb_hi + 33554432ul;

  prep_weights<<<2, 256, 0, stream>>>(Wq1, Wq2, Wql, Wk, Wv, wcat_hi, wcat_lo, wkv_hi, wkv_lo);
  kv_prep<<<Bb * Nn / 32, 256, 0, stream>>>(nodes, wkv_hi, wkv_lo, ekkP_hi, ekkP_lo,
                                            nodesP_hi, nodesP_lo);
  bias_prep<<<2048, 256, 0, stream>>>(cdist, ninf, eb_hi, eb_lo, logs, aalpha);
  nd_gemm<<<512, 256, 0, stream>>>(eb_hi, eb_lo, ekkP_hi, ekkP_lo, nd);
  aft_prep<<<2048, 256, 0, stream>>>(q1m, q2m, lnm, loadv, leftv, Wql, wcat_hi, wcat_lo,
                                     nd, aftP_hi, aftP_lo);
  score_softmax<<<Bb * Pp / 32, 512, 0, stream>>>(
      cdist, ninf, aftP_hi, aftP_lo, nodesP_hi, nodesP_lo, (float*)d_out, logs, palpha);
}

// Round 8
// 434.497 us; speedup vs baseline: 1.5800x; 1.2145x over previous
//
#include <hip/hip_runtime.h>
#include <math.h>

#define Bb 32
#define Pp 1024
#define Nn 1024

typedef unsigned short u16;
typedef __bf16 bf16x8 __attribute__((ext_vector_type(8)));
typedef float f32x4 __attribute__((ext_vector_type(4)));
typedef u16 us8 __attribute__((ext_vector_type(8)));
typedef u16 us4 __attribute__((ext_vector_type(4)));

#define MFMA __builtin_amdgcn_mfma_f32_16x16x32_bf16

static constexpr float INV_SQRT_E = 0.08838834764831845f;  // 1/sqrt(128)

__device__ __forceinline__ bf16x8 asbf(us8 v) { return __builtin_bit_cast(bf16x8, v); }

// RTN split: x ~= hi + lo to ~2^-17 rel
__device__ __forceinline__ void bsplit(float x, u16& h, u16& l) {
  unsigned u = __float_as_uint(x);
  unsigned r = u + 0x7FFF + ((u >> 16) & 1);
  h = (u16)(r >> 16);
  float hf = __uint_as_float((unsigned)h << 16);
  float lof = x - hf;
  unsigned u2 = __float_as_uint(lof);
  unsigned r2 = u2 + 0x7FFF + ((u2 >> 16) & 1);
  l = (u16)(r2 >> 16);
}

// trunc split: x ~= hi + lo to ~2^-16 rel, cheap
__device__ __forceinline__ void tsplit(float x, u16& h, u16& l) {
  unsigned u = __float_as_uint(x);
  h = (u16)(u >> 16);
  float lof = x - __uint_as_float(u & 0xFFFF0000u);
  l = (u16)(__float_as_uint(lof) >> 16);
}

__device__ __forceinline__ float fast_tanh(float x) {
  float ax = fabsf(x);
  float t = __expf(-2.0f * ax);
  float r = (1.0f - t) / (1.0f + t);
  return copysignf(r, x);
}

// ---------------- K0: transposed split weight planes ----------------
__global__ __launch_bounds__(256) void prep_weights(
    const float* __restrict__ Wq1, const float* __restrict__ Wq2,
    const float* __restrict__ Wql, const float* __restrict__ Wk,
    const float* __restrict__ Wv, u16* __restrict__ wcat_hi, u16* __restrict__ wcat_lo,
    u16* __restrict__ wkv_hi, u16* __restrict__ wkv_lo) {
  int t = threadIdx.x;
  if (blockIdx.x == 0) {
    for (int i = t; i < 128 * 384; i += 256) {
      int c = i / 384, k = i % 384;
      float v = (k < 128) ? Wq1[k * 128 + c]
                          : (k < 256) ? Wq2[(k - 128) * 128 + c] : Wql[(k - 256) * 128 + c];
      u16 h, l;
      bsplit(v, h, l);
      wcat_hi[i] = h;
      wcat_lo[i] = l;
    }
  } else {
    for (int i = t; i < 256 * 128; i += 256) {
      int c = i >> 7, k = i & 127;
      float v = (c < 128) ? Wk[k * 128 + c] : Wv[k * 128 + (c - 128)];
      u16 h, l;
      bsplit(v, h, l);
      wkv_hi[i] = h;
      wkv_lo[i] = l;
    }
  }
}

// ---------------- K1: k/v GEMM -> ekkP ([b][nch128][c256][8]) + nodesP ----------------
__global__ __launch_bounds__(256, 1) void kv_prep(
    const float* __restrict__ nodes, const u16* __restrict__ wkv_hi,
    const u16* __restrict__ wkv_lo, u16* __restrict__ ekkP_hi, u16* __restrict__ ekkP_lo,
    u16* __restrict__ nodesP_hi, u16* __restrict__ nodesP_lo) {
  __shared__ u16 a_hi[32 * 136], a_lo[32 * 136];
  __shared__ float kvbuf[32 * 264];
  const int t = threadIdx.x;
  const int xcd = blockIdx.x & 7, jj = blockIdx.x >> 3;
  const int b = xcd * 4 + (jj >> 5);
  const int n0 = (jj & 31) * 32;
  for (int i = t; i < 4096; i += 256) {
    int n = i >> 7, d = i & 127;
    float v = nodes[((long)(b * 1024 + n0 + n)) * 128 + d];
    u16 h, l;
    bsplit(v, h, l);
    a_hi[n * 136 + d] = h;
    a_lo[n * 136 + d] = l;
  }
  __syncthreads();
  const int lane = t & 63, w = t >> 6;
  const int lr = lane & 15, lg = lane >> 4;
  f32x4 acc0[2][4] = {}, acc1[2][4] = {};
#pragma unroll
  for (int ks = 0; ks < 4; ++ks) {
    us8 ah[2], al[2];
#pragma unroll
    for (int mt = 0; mt < 2; ++mt) {
      int ro = (lr + 16 * mt) * 136 + ks * 32 + lg * 8;
      ah[mt] = *(const us8*)&a_hi[ro];
      al[mt] = *(const us8*)&a_lo[ro];
    }
    us8 bh[4], bl[4];
#pragma unroll
    for (int cc = 0; cc < 4; ++cc) {
      long off = (long)((w * 4 + cc) * 16 + lr) * 128 + ks * 32 + lg * 8;
      bh[cc] = *(const us8*)&wkv_hi[off];
      bl[cc] = *(const us8*)&wkv_lo[off];
    }
#pragma unroll
    for (int mt = 0; mt < 2; ++mt)
#pragma unroll
      for (int cc = 0; cc < 4; ++cc) {
        acc0[mt][cc] = MFMA(asbf(ah[mt]), asbf(bh[cc]), acc0[mt][cc], 0, 0, 0);
        acc1[mt][cc] = MFMA(asbf(al[mt]), asbf(bh[cc]), acc1[mt][cc], 0, 0, 0);
        acc1[mt][cc] = MFMA(asbf(ah[mt]), asbf(bl[cc]), acc1[mt][cc], 0, 0, 0);
      }
  }
#pragma unroll
  for (int mt = 0; mt < 2; ++mt)
#pragma unroll
    for (int cc = 0; cc < 4; ++cc) {
      int c = (w * 4 + cc) * 16 + lr;
#pragma unroll
      for (int r = 0; r < 4; ++r)
        kvbuf[(lg * 4 + r + 16 * mt) * 264 + c] = acc0[mt][cc][r] + acc1[mt][cc][r];
    }
  __syncthreads();
#pragma unroll
  for (int jo = 0; jo < 4; ++jo) {
    int c = jo * 64 + (t & 63);
    int i4 = t >> 6;
    int kcol = (c < 128) ? c : (c - 128);
    us8 h8, l8;
#pragma unroll
    for (int jq = 0; jq < 8; ++jq) {
      int n = i4 * 8 + jq;
      float kv = kvbuf[n * 264 + kcol];
      float ek = __expf(kv);
      float val = (c < 128) ? ek * kvbuf[n * 264 + c + 128] : ek;
      u16 h, l;
      bsplit(val, h, l);
      h8[jq] = h;
      l8[jq] = l;
    }
    long o = (((long)b * 128 + (n0 >> 3) + i4) * 256 + c) * 8;
    *(us8*)&ekkP_hi[o] = h8;
    *(us8*)&ekkP_lo[o] = l8;
  }
  {
    int pl = t >> 7, r = t & 127;
    int dgrp = r >> 3, nb = r & 7;
    const u16* src = pl ? a_lo : a_hi;
    u16* dst = pl ? nodesP_lo : nodesP_hi;
#pragma unroll
    for (int i = 0; i < 4; ++i) {
      int n = nb + 8 * i;
      us8 v = *(const us8*)&src[n * 136 + dgrp * 8];
      *(us8*)&dst[(((long)(b * 16 + dgrp)) * 1024 + n0 + n) * 8] = v;
    }
  }
}

// ---------------- K2: e_bias planes, interleaved per tile in d_out ----------------
// tile t (16 rows): u16 base t*32768; hi [0,16384), lo [16384,32768). inner [nc128][pr16][8]
__global__ __launch_bounds__(256) void bias_prep(
    const float* __restrict__ cdist, const float* __restrict__ ninf,
    u16* __restrict__ eb, const float* __restrict__ logs, const float* __restrict__ aal) {
  const float c1 = logs[0] * aal[0];
  const int tile = blockIdx.x;
  const long prow = (long)tile * 16;
  const int t = threadIdx.x;
#pragma unroll 2
  for (int it = 0; it < 8; ++it) {
    int item = t + it * 256;  // nc*16 + pr
    int nc = item >> 4, pr = item & 15;
    long off = (prow + pr) * 1024 + nc * 8;
    float4 d0 = *(const float4*)&cdist[off];
    float4 d1 = *(const float4*)&cdist[off + 4];
    float4 f0 = *(const float4*)&ninf[off];
    float4 f1 = *(const float4*)&ninf[off + 4];
    float dv[8] = {d0.x, d0.y, d0.z, d0.w, d1.x, d1.y, d1.z, d1.w};
    float nv[8] = {f0.x, f0.y, f0.z, f0.w, f1.x, f1.y, f1.z, f1.w};
    us8 h8, l8;
#pragma unroll
    for (int jq = 0; jq < 8; ++jq) {
      float ebv = __expf(fmaf(-c1, dv[jq], nv[jq]));
      u16 h, l;
      tsplit(ebv, h, l);
      h8[jq] = h;
      l8[jq] = l;
    }
    long base = (long)tile * 32768 + (long)item * 8;
    *(us8*)&eb[base] = h8;
    *(us8*)&eb[base + 16384] = l8;
  }
}

// ---------------- K3: q GEMM + sigmoid -> qsig f32 [32K][128] ----------------
__global__ __launch_bounds__(256) void qsig_prep(
    const float* __restrict__ q1m, const float* __restrict__ q2m,
    const float* __restrict__ lnm, const float* __restrict__ loadv,
    const float* __restrict__ leftv, const float* __restrict__ Wql,
    const u16* __restrict__ wcat_hi, const u16* __restrict__ wcat_lo,
    float* __restrict__ qsig) {
  const int t = threadIdx.x;
  const int lane = t & 63, w = t >> 6;
  const int lr = lane & 15, lg = lane >> 4;
  const long p0 = (long)blockIdx.x * 16;
  const long arow = p0 + lr;
  f32x4 qacc[2] = {};
#pragma unroll 2
  for (int s = 0; s < 12; ++s) {
    const float* __restrict__ src = (s < 4) ? q1m : (s < 8) ? q2m : lnm;
    long ao = arow * 128 + (s & 3) * 32 + lg * 8;
    float4 a0 = *(const float4*)&src[ao];
    float4 a1 = *(const float4*)&src[ao + 4];
    float av[8] = {a0.x, a0.y, a0.z, a0.w, a1.x, a1.y, a1.z, a1.w};
    us8 ah, al;
#pragma unroll
    for (int jq = 0; jq < 8; ++jq) {
      u16 hh, ll;
      tsplit(av[jq], hh, ll);
      ah[jq] = hh;
      al[jq] = ll;
    }
#pragma unroll
    for (int cf = 0; cf < 2; ++cf) {
      int c = w * 32 + cf * 16 + lr;
      us8 bh = *(const us8*)&wcat_hi[c * 384 + s * 32 + lg * 8];
      us8 bl = *(const us8*)&wcat_lo[c * 384 + s * 32 + lg * 8];
      qacc[cf] = MFMA(asbf(ah), asbf(bh), qacc[cf], 0, 0, 0);
      qacc[cf] = MFMA(asbf(al), asbf(bh), qacc[cf], 0, 0, 0);
      qacc[cf] = MFMA(asbf(ah), asbf(bl), qacc[cf], 0, 0, 0);
    }
  }
#pragma unroll
  for (int cf = 0; cf < 2; ++cf) {
    int c = w * 32 + cf * 16 + lr;
    float wl1 = Wql[128 * 128 + c], wl2 = Wql[129 * 128 + c];
#pragma unroll
    for (int r = 0; r < 4; ++r) {
      int row = lg * 4 + r;
      float qv = qacc[cf][r] + loadv[p0 + row] * wl1 + leftv[p0 + row] * wl2;
      qsig[(p0 + row) * 128 + c] = 1.0f / (1.0f + __expf(-qv));
    }
  }
}

// ---------------- K4: [num|den] GEMM (128rows x 256cols x K1024) + AFT epilogue ----------------
// 256 blocks (1/CU), 256 thr / 4 waves (wr,wc in 2x2). Reg-staged 2-phase pipeline.
__global__ __launch_bounds__(256, 1) void ndaft_gemm(
    const u16* __restrict__ eb, const u16* __restrict__ ekkP_hi,
    const u16* __restrict__ ekkP_lo, const float* __restrict__ qsig,
    u16* __restrict__ aftP_hi, u16* __restrict__ aftP_lo) {
  __shared__ u16 lds[24576];  // A: [pt8][pl2][512] = 8K u16; B at 8192: [q4][pl2][c256][8]
  const int t = threadIdx.x;
  const int lane = t & 63, w = t >> 6;
  const int lr = lane & 15, lg = lane >> 4;
  const int wr = w >> 1, wc = w & 1;
  const int xcd = blockIdx.x & 7, g = blockIdx.x >> 3;
  const int b = xcd * 4 + (g & 3);
  const int pt = g >> 2;  // 0..7, 128 rows
  const int tile0 = b * 64 + pt * 8;
  const long bp = (long)b * Pp + pt * 128;

  us8 st[12];
  auto load_step = [&](int s) {
#pragma unroll
    for (int i = 0; i < 12; ++i) {
      int f = i * 256 + t;
      const u16* src;
      if (f < 1024) {
        int ptile = f >> 7, pl = (f >> 6) & 1, off = f & 63;
        src = eb + ((long)(tile0 + ptile) * 32768) + pl * 16384 + s * 512 + off * 8;
      } else {
        int g2 = f - 1024;
        int q = g2 >> 9, pl = (g2 >> 8) & 1, c = g2 & 255;
        const u16* bP = pl ? ekkP_lo : ekkP_hi;
        src = bP + (((long)b * 128 + s * 4 + q) * 256 + c) * 8;
      }
      st[i] = *(const us8*)src;
    }
  };
  auto write_step = [&]() {
#pragma unroll
    for (int i = 0; i < 12; ++i) {
      int f = i * 256 + t;
      *(us8*)&lds[f * 8] = st[i];
    }
  };

  f32x4 acc[4][8] = {};
  load_step(0);
  write_step();
  __syncthreads();
  for (int s = 0; s < 32; ++s) {
    if (s < 31) load_step(s + 1);  // in flight across compute
    us8 ah[4], al[4];
#pragma unroll
    for (int mt = 0; mt < 4; ++mt) {
      int ptile = wr * 4 + mt;
      ah[mt] = *(const us8*)&lds[ptile * 1024 + (lg * 16 + lr) * 8];
      al[mt] = *(const us8*)&lds[ptile * 1024 + 512 + (lg * 16 + lr) * 8];
    }
#pragma unroll
    for (int ct = 0; ct < 8; ++ct) {
      int c = (ct < 4) ? (wc * 64 + ct * 16 + lr) : (128 + wc * 64 + (ct - 4) * 16 + lr);
      us8 bh = *(const us8*)&lds[8192 + ((lg * 2) * 256 + c) * 8];
      us8 bl = *(const us8*)&lds[8192 + ((lg * 2 + 1) * 256 + c) * 8];
#pragma unroll
      for (int mt = 0; mt < 4; ++mt) {
        acc[mt][ct] = MFMA(asbf(ah[mt]), asbf(bh), acc[mt][ct], 0, 0, 0);
        acc[mt][ct] = MFMA(asbf(al[mt]), asbf(bh), acc[mt][ct], 0, 0, 0);
        acc[mt][ct] = MFMA(asbf(ah[mt]), asbf(bl), acc[mt][ct], 0, 0, 0);
      }
    }
    __syncthreads();  // all waves done reading stage s
    if (s < 31) {
      write_step();   // vmcnt wait inserted here by compiler
      __syncthreads();
    }
  }
  // epilogue: aft = sig * num/(den+eps) -> split bf16, packed aftP
#pragma unroll
  for (int mt = 0; mt < 4; ++mt)
#pragma unroll
    for (int ct = 0; ct < 4; ++ct) {
      int cn = wc * 64 + ct * 16 + lr;
      int nc = cn >> 3, jq = cn & 7;
#pragma unroll
      for (int r = 0; r < 4; ++r) {
        long gr = bp + wr * 64 + mt * 16 + lg * 4 + r;
        float sig = qsig[gr * 128 + cn];
        float aftv = sig * (acc[mt][ct][r] / (acc[mt][ct + 4][r] + 1e-20f));
        u16 h, l;
        bsplit(aftv, h, l);
        long idx = (gr >> 4) * 2048 + (nc * 16 + (gr & 15)) * 8 + jq;
        aftP_hi[idx] = h;
        aftP_lo[idx] = l;
      }
    }
}

// ---------------- K5: score GEMM (transposed) + tanh-clip softmax ----------------
// bias recovered from eb: sb = (c2/c1)*ln(eb_hi+eb_lo) = -c2*d + (c2/c1)*ninf (exact for ninf=0)
__global__ __launch_bounds__(512, 4) void score_softmax(
    const u16* eb, const u16* __restrict__ aftP_hi, const u16* __restrict__ aftP_lo,
    const u16* __restrict__ nodesP_hi, const u16* __restrict__ nodesP_lo,
    float* out, const float* __restrict__ logs, const float* __restrict__ aal,
    const float* __restrict__ pal) {
  __shared__ float sbuf[32 * 264];
  __shared__ float psum[32 * 4];
  __shared__ float invb[32];
  const int t = threadIdx.x;
  const int lane = t & 63, w = t >> 6;
  const int lr = lane & 15, lg = lane >> 4;
  const int rg = w & 1, cg = w >> 1;
  const int xcd = blockIdx.x & 7, j = blockIdx.x >> 3;
  const int b = xcd * 4 + (j >> 5);
  const int p0 = (j & 31) * 32;
  const long bp = (long)b * Pp + p0;
  const float c1 = logs[0] * aal[0];
  const float ratio = logs[0] * pal[0] / c1;  // c2/c1
  const int tileb = b * 64 + (p0 >> 4);

  // P4: transposed score GEMM: lane holds (n = cg*256+cf*16+lg*4+r, p = rg*16+lr)
  f32x4 sacc[16] = {};
#pragma unroll
  for (int ks = 0; ks < 4; ++ks) {
    long aoff = (long)(tileb + rg) * 2048 + ((long)((ks * 4 + lg) * 16 + lr)) * 8;
    us8 ah = *(const us8*)&aftP_hi[aoff];
    us8 al = *(const us8*)&aftP_lo[aoff];
    long nb = ((long)(b * 16 + ks * 4 + lg)) * 1024;
#pragma unroll
    for (int cf = 0; cf < 16; ++cf) {
      long o = (nb + cg * 256 + cf * 16 + lr) * 8;
      us8 bh = *(const us8*)&nodesP_hi[o];
      us8 bl = *(const us8*)&nodesP_lo[o];
      sacc[cf] = MFMA(asbf(bh), asbf(ah), sacc[cf], 0, 0, 0);
      sacc[cf] = MFMA(asbf(bl), asbf(ah), sacc[cf], 0, 0, 0);
      sacc[cf] = MFMA(asbf(bh), asbf(al), sacc[cf], 0, 0, 0);
    }
  }

  // P5a: bias from eb + tanh-clip + exp; per-lane p = rg*16+lr fixed
  const long ebtile = (long)(tileb + rg) * 32768;
  float rs = 0.f;
#pragma unroll
  for (int cf = 0; cf < 16; ++cf) {
    int nc = cg * 32 + cf * 2 + (lg >> 1);
    int j0 = (lg & 1) * 4;
    long o = ebtile + (nc * 16 + lr) * 8 + j0;
    us4 h4 = *(const us4*)&eb[o];
    us4 l4 = *(const us4*)&eb[o + 16384];
#pragma unroll
    for (int r = 0; r < 4; ++r) {
      float ebf = __uint_as_float((unsigned)h4[r] << 16) +
                  __uint_as_float((unsigned)l4[r] << 16);
      float sb = ratio * __logf(ebf);
      float sv = fmaf(sacc[cf][r], INV_SQRT_E, sb);
      float e = __expf(10.0f * fast_tanh(sv));
      e = (ebf > 0.f) ? e : 0.f;  // -inf mask guard
      sacc[cf][r] = e;
      rs += e;
    }
  }
  // P5b: reduce over lg (xor 16,32) then over cg via psum
  rs += __shfl_xor(rs, 16);
  rs += __shfl_xor(rs, 32);
  if (lg == 0) psum[(rg * 16 + lr) * 4 + cg] = rs;
  __syncthreads();
  if (t < 32)
    invb[t] = 1.0f / (psum[t * 4] + psum[t * 4 + 1] + psum[t * 4 + 2] + psum[t * 4 + 3]);
  __syncthreads();

  // P5c: normalize (per-lane uniform) + LDS-staged coalesced stores
  const float inv = invb[rg * 16 + lr];
#pragma unroll 1
  for (int c = 0; c < 4; ++c) {
    if (cg == c) {
      int prow = rg * 16 + lr;
#pragma unroll
      for (int cf = 0; cf < 16; ++cf) {
        float4 v;
        v.x = sacc[cf][0] * inv;
        v.y = sacc[cf][1] * inv;
        v.z = sacc[cf][2] * inv;
        v.w = sacc[cf][3] * inv;
        *(float4*)&sbuf[prow * 264 + cf * 16 + lg * 4] = v;
      }
    }
    __syncthreads();
    {
      int row = t >> 4, cq = t & 15;
      long ro = (bp + row) * (long)Nn + c * 256;
#pragma unroll
      for (int i = 0; i < 4; ++i)
        *(float4*)&out[ro + cq * 4 + i * 64] =
            *(const float4*)&sbuf[row * 264 + cq * 4 + i * 64];
    }
    __syncthreads();
  }
}

extern "C" void kernel_launch(void* const* d_in, const int* in_sizes, int n_in,
                              void* d_out, int out_size, void* d_ws, size_t ws_size,
                              hipStream_t stream) {
  const float* nodes = (const float*)d_in[0];
  const float* q1m = (const float*)d_in[1];
  const float* q2m = (const float*)d_in[2];
  const float* lnm = (const float*)d_in[3];
  const float* loadv = (const float*)d_in[4];
  const float* leftv = (const float*)d_in[5];
  const float* cdist = (const float*)d_in[6];
  const float* logs = (const float*)d_in[7];
  const float* ninf = (const float*)d_in[8];
  const float* Wq1 = (const float*)d_in[9];
  const float* Wq2 = (const float*)d_in[10];
  const float* Wql = (const float*)d_in[11];
  const float* Wk = (const float*)d_in[12];
  const float* Wv = (const float*)d_in[13];
  const float* aalpha = (const float*)d_in[14];
  const float* palpha = (const float*)d_in[15];

  char* ws = (char*)d_ws;
  u16* ekkP_hi = (u16*)ws;                      // 16 MB
  u16* ekkP_lo = (u16*)(ws + (16ul << 20));     // 16 MB
  u16* nodesP_hi = (u16*)(ws + (32ul << 20));   // 8 MB
  u16* nodesP_lo = (u16*)(ws + (40ul << 20));   // 8 MB
  float* qsig = (float*)(ws + (48ul << 20));    // 16 MB
  u16* aftP_hi = (u16*)(ws + (64ul << 20));     // 8 MB
  u16* aftP_lo = (u16*)(ws + (72ul << 20));     // 8 MB
  u16* wcat_hi = (u16*)(ws + (80ul << 20));
  u16* wcat_lo = wcat_hi + 128 * 384;
  u16* wkv_hi = wcat_lo + 128 * 384;
  u16* wkv_lo = wkv_hi + 256 * 128;
  u16* eb = (u16*)d_out;  // e_bias interleaved per-tile; overwritten in-place by score

  prep_weights<<<2, 256, 0, stream>>>(Wq1, Wq2, Wql, Wk, Wv, wcat_hi, wcat_lo, wkv_hi, wkv_lo);
  kv_prep<<<Bb * Nn / 32, 256, 0, stream>>>(nodes, wkv_hi, wkv_lo, ekkP_hi, ekkP_lo,
                                            nodesP_hi, nodesP_lo);
  bias_prep<<<2048, 256, 0, stream>>>(cdist, ninf, eb, logs, aalpha);
  qsig_prep<<<2048, 256, 0, stream>>>(q1m, q2m, lnm, loadv, leftv, Wql, wcat_hi, wcat_lo,
                                      qsig);
  ndaft_gemm<<<256, 256, 0, stream>>>(eb, ekkP_hi, ekkP_lo, qsig, aftP_hi, aftP_lo);
  score_softmax<<<Bb * Pp / 32, 512, 0, stream>>>(
      eb, aftP_hi, aftP_lo, nodesP_hi, nodesP_lo, (float*)d_out, logs, aalpha, palpha);
}

// Round 9
// 374.991 us; speedup vs baseline: 1.8308x; 1.1587x over previous
//
#include <hip/hip_runtime.h>
#include <math.h>

#define Bb 32
#define Pp 1024
#define Nn 1024

typedef unsigned short u16;
typedef __bf16 bf16x8 __attribute__((ext_vector_type(8)));
typedef float f32x4 __attribute__((ext_vector_type(4)));
typedef u16 us8 __attribute__((ext_vector_type(8)));
typedef u16 us4 __attribute__((ext_vector_type(4)));

#define MFMA __builtin_amdgcn_mfma_f32_16x16x32_bf16

static constexpr float INV_SQRT_E = 0.08838834764831845f;  // 1/sqrt(128)

__device__ __forceinline__ bf16x8 asbf(us8 v) { return __builtin_bit_cast(bf16x8, v); }

// RTN split: x ~= hi + lo to ~2^-17 rel
__device__ __forceinline__ void bsplit(float x, u16& h, u16& l) {
  unsigned u = __float_as_uint(x);
  unsigned r = u + 0x7FFF + ((u >> 16) & 1);
  h = (u16)(r >> 16);
  float hf = __uint_as_float((unsigned)h << 16);
  float lof = x - hf;
  unsigned u2 = __float_as_uint(lof);
  unsigned r2 = u2 + 0x7FFF + ((u2 >> 16) & 1);
  l = (u16)(r2 >> 16);
}

// trunc split: x ~= hi + lo to ~2^-16 rel, cheap
__device__ __forceinline__ void tsplit(float x, u16& h, u16& l) {
  unsigned u = __float_as_uint(x);
  h = (u16)(u >> 16);
  float lof = x - __uint_as_float(u & 0xFFFF0000u);
  l = (u16)(__float_as_uint(lof) >> 16);
}

__device__ __forceinline__ float fast_tanh(float x) {
  float ax = fabsf(x);
  float t = __expf(-2.0f * ax);
  float r = (1.0f - t) / (1.0f + t);
  return copysignf(r, x);
}

// ---------------- K0: transposed split weight planes ----------------
__global__ __launch_bounds__(256) void prep_weights(
    const float* __restrict__ Wq1, const float* __restrict__ Wq2,
    const float* __restrict__ Wql, const float* __restrict__ Wk,
    const float* __restrict__ Wv, u16* __restrict__ wcat_hi, u16* __restrict__ wcat_lo,
    u16* __restrict__ wkv_hi, u16* __restrict__ wkv_lo) {
  int t = threadIdx.x;
  if (blockIdx.x == 0) {
    for (int i = t; i < 128 * 384; i += 256) {
      int c = i / 384, k = i % 384;
      float v = (k < 128) ? Wq1[k * 128 + c]
                          : (k < 256) ? Wq2[(k - 128) * 128 + c] : Wql[(k - 256) * 128 + c];
      u16 h, l;
      bsplit(v, h, l);
      wcat_hi[i] = h;
      wcat_lo[i] = l;
    }
  } else {
    for (int i = t; i < 256 * 128; i += 256) {
      int c = i >> 7, k = i & 127;
      float v = (c < 128) ? Wk[k * 128 + c] : Wv[k * 128 + (c - 128)];
      u16 h, l;
      bsplit(v, h, l);
      wkv_hi[i] = h;
      wkv_lo[i] = l;
    }
  }
}

// ---------------- K1: k/v GEMM -> ekkP ([b][nch128][c256][8]) + nodesP ----------------
__global__ __launch_bounds__(256, 1) void kv_prep(
    const float* __restrict__ nodes, const u16* __restrict__ wkv_hi,
    const u16* __restrict__ wkv_lo, u16* __restrict__ ekkP_hi, u16* __restrict__ ekkP_lo,
    u16* __restrict__ nodesP_hi, u16* __restrict__ nodesP_lo) {
  __shared__ u16 a_hi[32 * 136], a_lo[32 * 136];
  __shared__ float kvbuf[32 * 264];
  const int t = threadIdx.x;
  const int xcd = blockIdx.x & 7, jj = blockIdx.x >> 3;
  const int b = xcd * 4 + (jj >> 5);
  const int n0 = (jj & 31) * 32;
  for (int i = t; i < 4096; i += 256) {
    int n = i >> 7, d = i & 127;
    float v = nodes[((long)(b * 1024 + n0 + n)) * 128 + d];
    u16 h, l;
    bsplit(v, h, l);
    a_hi[n * 136 + d] = h;
    a_lo[n * 136 + d] = l;
  }
  __syncthreads();
  const int lane = t & 63, w = t >> 6;
  const int lr = lane & 15, lg = lane >> 4;
  f32x4 acc0[2][4] = {}, acc1[2][4] = {};
#pragma unroll
  for (int ks = 0; ks < 4; ++ks) {
    us8 ah[2], al[2];
#pragma unroll
    for (int mt = 0; mt < 2; ++mt) {
      int ro = (lr + 16 * mt) * 136 + ks * 32 + lg * 8;
      ah[mt] = *(const us8*)&a_hi[ro];
      al[mt] = *(const us8*)&a_lo[ro];
    }
    us8 bh[4], bl[4];
#pragma unroll
    for (int cc = 0; cc < 4; ++cc) {
      long off = (long)((w * 4 + cc) * 16 + lr) * 128 + ks * 32 + lg * 8;
      bh[cc] = *(const us8*)&wkv_hi[off];
      bl[cc] = *(const us8*)&wkv_lo[off];
    }
#pragma unroll
    for (int mt = 0; mt < 2; ++mt)
#pragma unroll
      for (int cc = 0; cc < 4; ++cc) {
        acc0[mt][cc] = MFMA(asbf(ah[mt]), asbf(bh[cc]), acc0[mt][cc], 0, 0, 0);
        acc1[mt][cc] = MFMA(asbf(al[mt]), asbf(bh[cc]), acc1[mt][cc], 0, 0, 0);
        acc1[mt][cc] = MFMA(asbf(ah[mt]), asbf(bl[cc]), acc1[mt][cc], 0, 0, 0);
      }
  }
#pragma unroll
  for (int mt = 0; mt < 2; ++mt)
#pragma unroll
    for (int cc = 0; cc < 4; ++cc) {
      int c = (w * 4 + cc) * 16 + lr;
#pragma unroll
      for (int r = 0; r < 4; ++r)
        kvbuf[(lg * 4 + r + 16 * mt) * 264 + c] = acc0[mt][cc][r] + acc1[mt][cc][r];
    }
  __syncthreads();
#pragma unroll
  for (int jo = 0; jo < 4; ++jo) {
    int c = jo * 64 + (t & 63);
    int i4 = t >> 6;
    int kcol = (c < 128) ? c : (c - 128);
    us8 h8, l8;
#pragma unroll
    for (int jq = 0; jq < 8; ++jq) {
      int n = i4 * 8 + jq;
      float kv = kvbuf[n * 264 + kcol];
      float ek = __expf(kv);
      float val = (c < 128) ? ek * kvbuf[n * 264 + c + 128] : ek;
      u16 h, l;
      bsplit(val, h, l);
      h8[jq] = h;
      l8[jq] = l;
    }
    long o = (((long)b * 128 + (n0 >> 3) + i4) * 256 + c) * 8;
    *(us8*)&ekkP_hi[o] = h8;
    *(us8*)&ekkP_lo[o] = l8;
  }
  {
    int pl = t >> 7, r = t & 127;
    int dgrp = r >> 3, nb = r & 7;
    const u16* src = pl ? a_lo : a_hi;
    u16* dst = pl ? nodesP_lo : nodesP_hi;
#pragma unroll
    for (int i = 0; i < 4; ++i) {
      int n = nb + 8 * i;
      us8 v = *(const us8*)&src[n * 136 + dgrp * 8];
      *(us8*)&dst[(((long)(b * 16 + dgrp)) * 1024 + n0 + n) * 8] = v;
    }
  }
}

// ---------------- K2: q GEMM + sigmoid -> qsig f32 [32K][128] ----------------
__global__ __launch_bounds__(256) void qsig_prep(
    const float* __restrict__ q1m, const float* __restrict__ q2m,
    const float* __restrict__ lnm, const float* __restrict__ loadv,
    const float* __restrict__ leftv, const float* __restrict__ Wql,
    const u16* __restrict__ wcat_hi, const u16* __restrict__ wcat_lo,
    float* __restrict__ qsig) {
  const int t = threadIdx.x;
  const int lane = t & 63, w = t >> 6;
  const int lr = lane & 15, lg = lane >> 4;
  const long p0 = (long)blockIdx.x * 16;
  const long arow = p0 + lr;
  f32x4 qacc[2] = {};
#pragma unroll 2
  for (int s = 0; s < 12; ++s) {
    const float* __restrict__ src = (s < 4) ? q1m : (s < 8) ? q2m : lnm;
    long ao = arow * 128 + (s & 3) * 32 + lg * 8;
    float4 a0 = *(const float4*)&src[ao];
    float4 a1 = *(const float4*)&src[ao + 4];
    float av[8] = {a0.x, a0.y, a0.z, a0.w, a1.x, a1.y, a1.z, a1.w};
    us8 ah, al;
#pragma unroll
    for (int jq = 0; jq < 8; ++jq) {
      u16 hh, ll;
      tsplit(av[jq], hh, ll);
      ah[jq] = hh;
      al[jq] = ll;
    }
#pragma unroll
    for (int cf = 0; cf < 2; ++cf) {
      int c = w * 32 + cf * 16 + lr;
      us8 bh = *(const us8*)&wcat_hi[c * 384 + s * 32 + lg * 8];
      us8 bl = *(const us8*)&wcat_lo[c * 384 + s * 32 + lg * 8];
      qacc[cf] = MFMA(asbf(ah), asbf(bh), qacc[cf], 0, 0, 0);
      qacc[cf] = MFMA(asbf(al), asbf(bh), qacc[cf], 0, 0, 0);
      qacc[cf] = MFMA(asbf(ah), asbf(bl), qacc[cf], 0, 0, 0);
    }
  }
#pragma unroll
  for (int cf = 0; cf < 2; ++cf) {
    int c = w * 32 + cf * 16 + lr;
    float wl1 = Wql[128 * 128 + c], wl2 = Wql[129 * 128 + c];
#pragma unroll
    for (int r = 0; r < 4; ++r) {
      int row = lg * 4 + r;
      float qv = qacc[cf][r] + loadv[p0 + row] * wl1 + leftv[p0 + row] * wl2;
      qsig[(p0 + row) * 128 + c] = 1.0f / (1.0f + __expf(-qv));
    }
  }
}

// ---------------- K3: fused bias + [num|den] GEMM (64r x 256c x K1024) + AFT epilogue ----------------
// 512 blocks (2/CU), 256 thr / 4 waves (wr=w>>1, wc=w&1; wave tile 32x128).
// e_bias computed in-register from cdist/ninf during staging; bias16 u16 plane emitted to d_out.
__global__ __launch_bounds__(256, 2) void ndaft_gemm(
    const float* __restrict__ cdist, const float* __restrict__ ninf,
    const u16* __restrict__ ekkP_hi, const u16* __restrict__ ekkP_lo,
    const float* __restrict__ qsig, u16* __restrict__ aftP_hi,
    u16* __restrict__ aftP_lo, u16* __restrict__ bias16,
    const float* __restrict__ logs, const float* __restrict__ aal,
    const float* __restrict__ pal) {
  __shared__ u16 lds[20480];  // A: [pt4][pl2][oct4][pr16][8] = 4096 u16; B at 4096: [oct4][pl2][c256][8]
  const int t = threadIdx.x;
  const int lane = t & 63, w = t >> 6;
  const int lr = lane & 15, lg = lane >> 4;
  const int wr = w >> 1, wc = w & 1;
  const int xcd = blockIdx.x & 7, g = blockIdx.x >> 3;
  const int b = xcd * 4 + (g & 3);
  const int pt = g >> 2;  // 0..15, 64 rows each
  const long bp = (long)b * Pp + pt * 64;
  const float c1 = logs[0] * aal[0];
  const float c2 = logs[0] * pal[0];

  const int srow = t >> 2, soct = t & 3;  // staging: row 0..63, K-oct 0..3
  const long arow = bp + srow;
  const long tbase = (arow >> 4) * 32768;  // bias16 tile base (u16 idx)
  const int pr = srow & 15, ptile = srow >> 4;

  float4 d0, d1, f0, f1;
  us8 bst[8];
  auto load_regs = [&](int s) {
    long ao = arow * 1024 + s * 32 + soct * 8;
    d0 = *(const float4*)&cdist[ao];
    d1 = *(const float4*)&cdist[ao + 4];
    f0 = *(const float4*)&ninf[ao];
    f1 = *(const float4*)&ninf[ao + 4];
#pragma unroll
    for (int i = 0; i < 8; ++i) {
      int u = i * 256 + t;
      int oct = u >> 9, pl = (u >> 8) & 1, c = u & 255;
      const u16* bP = pl ? ekkP_lo : ekkP_hi;
      bst[i] = *(const us8*)&bP[(((long)b * 128 + s * 4 + oct) * 256 + c) * 8];
    }
  };

  us8 ebh, ebl;
  auto compute_eb = [&](int s) {
    float dv[8] = {d0.x, d0.y, d0.z, d0.w, d1.x, d1.y, d1.z, d1.w};
    float nv[8] = {f0.x, f0.y, f0.z, f0.w, f1.x, f1.y, f1.z, f1.w};
    us8 q8;
#pragma unroll
    for (int jq = 0; jq < 8; ++jq) {
      float e = __expf(fmaf(-c1, dv[jq], nv[jq]));
      u16 h, l;
      tsplit(e, h, l);
      ebh[jq] = h;
      ebl[jq] = l;
      float x = fminf(fmaxf(c2 * dv[jq], 0.f), 15.999f);
      q8[jq] = (nv[jq] < -1e5f) ? (u16)0xFFFF : (u16)(x * 4096.f + 0.5f);
    }
    *(us8*)&bias16[tbase + ((s * 4 + soct) * 16 + pr) * 8] = q8;
  };

  auto write_lds = [&]() {
    *(us8*)&lds[((ptile * 2 + 0) * 4 + soct) * 128 + pr * 8] = ebh;
    *(us8*)&lds[((ptile * 2 + 1) * 4 + soct) * 128 + pr * 8] = ebl;
#pragma unroll
    for (int i = 0; i < 8; ++i) {
      int u = i * 256 + t;
      int oct = u >> 9, pl = (u >> 8) & 1, c = u & 255;
      *(us8*)&lds[4096 + ((oct * 2 + pl) * 256 + c) * 8] = bst[i];
    }
  };

  f32x4 acc[2][8] = {};
  load_regs(0);
  for (int s = 0; s < 32; ++s) {
    compute_eb(s);
    __syncthreads();  // prior stage's LDS reads complete
    write_lds();
    __syncthreads();
    if (s < 31) load_regs(s + 1);  // in flight under MFMA
    us8 ah[2], al[2];
#pragma unroll
    for (int mt = 0; mt < 2; ++mt) {
      int ptl = wr * 2 + mt;
      ah[mt] = *(const us8*)&lds[((ptl * 2 + 0) * 4 + lg) * 128 + lr * 8];
      al[mt] = *(const us8*)&lds[((ptl * 2 + 1) * 4 + lg) * 128 + lr * 8];
    }
#pragma unroll
    for (int ct = 0; ct < 8; ++ct) {
      int c = (ct < 4) ? (wc * 64 + ct * 16 + lr) : (128 + wc * 64 + (ct - 4) * 16 + lr);
      us8 bh = *(const us8*)&lds[4096 + ((lg * 2 + 0) * 256 + c) * 8];
      us8 bl = *(const us8*)&lds[4096 + ((lg * 2 + 1) * 256 + c) * 8];
#pragma unroll
      for (int mt = 0; mt < 2; ++mt) {
        acc[mt][ct] = MFMA(asbf(ah[mt]), asbf(bh), acc[mt][ct], 0, 0, 0);
        acc[mt][ct] = MFMA(asbf(al[mt]), asbf(bh), acc[mt][ct], 0, 0, 0);
        acc[mt][ct] = MFMA(asbf(ah[mt]), asbf(bl), acc[mt][ct], 0, 0, 0);
      }
    }
  }
  // epilogue: aft = sig * num/(den+eps) -> split bf16, packed aftP
#pragma unroll
  for (int mt = 0; mt < 2; ++mt)
#pragma unroll
    for (int ct = 0; ct < 4; ++ct) {
      int cn = wc * 64 + ct * 16 + lr;
      int nc = cn >> 3, jq = cn & 7;
#pragma unroll
      for (int r = 0; r < 4; ++r) {
        long gr = bp + wr * 32 + mt * 16 + lg * 4 + r;
        float sig = qsig[gr * 128 + cn];
        float aftv = sig * (acc[mt][ct][r] / (acc[mt][ct + 4][r] + 1e-20f));
        u16 h, l;
        bsplit(aftv, h, l);
        long idx = (gr >> 4) * 2048 + (nc * 16 + (gr & 15)) * 8 + jq;
        aftP_hi[idx] = h;
        aftP_lo[idx] = l;
      }
    }
}

// ---------------- K4: score GEMM (transposed) + tanh-clip softmax ----------------
// bias read from u16 fixed-point plane (in d_out, first 32KB of each tile's region)
__global__ __launch_bounds__(512, 4) void score_softmax(
    const u16* bias16, const u16* __restrict__ aftP_hi, const u16* __restrict__ aftP_lo,
    const u16* __restrict__ nodesP_hi, const u16* __restrict__ nodesP_lo,
    float* out) {
  __shared__ float sbuf[32 * 264];
  __shared__ float psum[32 * 4];
  __shared__ float invb[32];
  const int t = threadIdx.x;
  const int lane = t & 63, w = t >> 6;
  const int lr = lane & 15, lg = lane >> 4;
  const int rg = w & 1, cg = w >> 1;
  const int xcd = blockIdx.x & 7, j = blockIdx.x >> 3;
  const int b = xcd * 4 + (j >> 5);
  const int p0 = (j & 31) * 32;
  const long bp = (long)b * Pp + p0;
  const int tileb = b * 64 + (p0 >> 4);

  // P4: transposed score GEMM: lane holds (n = cg*256+cf*16+lg*4+r, p = rg*16+lr)
  f32x4 sacc[16] = {};
#pragma unroll
  for (int ks = 0; ks < 4; ++ks) {
    long aoff = (long)(tileb + rg) * 2048 + ((long)((ks * 4 + lg) * 16 + lr)) * 8;
    us8 ah = *(const us8*)&aftP_hi[aoff];
    us8 al = *(const us8*)&aftP_lo[aoff];
    long nb = ((long)(b * 16 + ks * 4 + lg)) * 1024;
#pragma unroll
    for (int cf = 0; cf < 16; ++cf) {
      long o = (nb + cg * 256 + cf * 16 + lr) * 8;
      us8 bh = *(const us8*)&nodesP_hi[o];
      us8 bl = *(const us8*)&nodesP_lo[o];
      sacc[cf] = MFMA(asbf(bh), asbf(ah), sacc[cf], 0, 0, 0);
      sacc[cf] = MFMA(asbf(bl), asbf(ah), sacc[cf], 0, 0, 0);
      sacc[cf] = MFMA(asbf(bh), asbf(al), sacc[cf], 0, 0, 0);
    }
  }

  // P5a: fixed-point bias + tanh-clip + exp; per-lane p = rg*16+lr fixed
  const long btile = (long)(tileb + rg) * 32768;
  float rs = 0.f;
#pragma unroll
  for (int cf = 0; cf < 16; ++cf) {
    int nc = cg * 32 + cf * 2 + (lg >> 1);
    int j0 = (lg & 1) * 4;
    us4 q4 = *(const us4*)&bias16[btile + (nc * 16 + lr) * 8 + j0];
#pragma unroll
    for (int r = 0; r < 4; ++r) {
      u16 qv = q4[r];
      float sv = fmaf(sacc[cf][r], INV_SQRT_E, (float)qv * -2.44140625e-4f);
      float e = __expf(10.0f * fast_tanh(sv));
      e = (qv == (u16)0xFFFF) ? 0.f : e;
      sacc[cf][r] = e;
      rs += e;
    }
  }
  // P5b: reduce over lg (xor 16,32) then over cg via psum
  rs += __shfl_xor(rs, 16);
  rs += __shfl_xor(rs, 32);
  if (lg == 0) psum[(rg * 16 + lr) * 4 + cg] = rs;
  __syncthreads();
  if (t < 32)
    invb[t] = 1.0f / (psum[t * 4] + psum[t * 4 + 1] + psum[t * 4 + 2] + psum[t * 4 + 3]);
  __syncthreads();

  // P5c: normalize (per-lane uniform) + LDS-staged coalesced stores
  const float inv = invb[rg * 16 + lr];
#pragma unroll 1
  for (int c = 0; c < 4; ++c) {
    if (cg == c) {
      int prow = rg * 16 + lr;
#pragma unroll
      for (int cf = 0; cf < 16; ++cf) {
        float4 v;
        v.x = sacc[cf][0] * inv;
        v.y = sacc[cf][1] * inv;
        v.z = sacc[cf][2] * inv;
        v.w = sacc[cf][3] * inv;
        *(float4*)&sbuf[prow * 264 + cf * 16 + lg * 4] = v;
      }
    }
    __syncthreads();
    {
      int row = t >> 4, cq = t & 15;
      long ro = (bp + row) * (long)Nn + c * 256;
#pragma unroll
      for (int i = 0; i < 4; ++i)
        *(float4*)&out[ro + cq * 4 + i * 64] =
            *(const float4*)&sbuf[row * 264 + cq * 4 + i * 64];
    }
    __syncthreads();
  }
}

extern "C" void kernel_launch(void* const* d_in, const int* in_sizes, int n_in,
                              void* d_out, int out_size, void* d_ws, size_t ws_size,
                              hipStream_t stream) {
  const float* nodes = (const float*)d_in[0];
  const float* q1m = (const float*)d_in[1];
  const float* q2m = (const float*)d_in[2];
  const float* lnm = (const float*)d_in[3];
  const float* loadv = (const float*)d_in[4];
  const float* leftv = (const float*)d_in[5];
  const float* cdist = (const float*)d_in[6];
  const float* logs = (const float*)d_in[7];
  const float* ninf = (const float*)d_in[8];
  const float* Wq1 = (const float*)d_in[9];
  const float* Wq2 = (const float*)d_in[10];
  const float* Wql = (const float*)d_in[11];
  const float* Wk = (const float*)d_in[12];
  const float* Wv = (const float*)d_in[13];
  const float* aalpha = (const float*)d_in[14];
  const float* palpha = (const float*)d_in[15];

  char* ws = (char*)d_ws;
  u16* ekkP_hi = (u16*)ws;                      // 16 MB
  u16* ekkP_lo = (u16*)(ws + (16ul << 20));     // 16 MB
  u16* nodesP_hi = (u16*)(ws + (32ul << 20));   // 8 MB
  u16* nodesP_lo = (u16*)(ws + (40ul << 20));   // 8 MB
  float* qsig = (float*)(ws + (48ul << 20));    // 16 MB
  u16* aftP_hi = (u16*)(ws + (64ul << 20));     // 8 MB
  u16* aftP_lo = (u16*)(ws + (72ul << 20));     // 8 MB
  u16* wcat_hi = (u16*)(ws + (80ul << 20));
  u16* wcat_lo = wcat_hi + 128 * 384;
  u16* wkv_hi = wcat_lo + 128 * 384;
  u16* wkv_lo = wkv_hi + 256 * 128;
  // bias16 lives in the first 32KB of each 64KB out-tile region; score reads
  // its own tiles before overwriting them.
  u16* bias16 = (u16*)d_out;

  prep_weights<<<2, 256, 0, stream>>>(Wq1, Wq2, Wql, Wk, Wv, wcat_hi, wcat_lo, wkv_hi, wkv_lo);
  kv_prep<<<Bb * Nn / 32, 256, 0, stream>>>(nodes, wkv_hi, wkv_lo, ekkP_hi, ekkP_lo,
                                            nodesP_hi, nodesP_lo);
  qsig_prep<<<2048, 256, 0, stream>>>(q1m, q2m, lnm, loadv, leftv, Wql, wcat_hi, wcat_lo,
                                      qsig);
  ndaft_gemm<<<512, 256, 0, stream>>>(cdist, ninf, ekkP_hi, ekkP_lo, qsig, aftP_hi,
                                      aftP_lo, bias16, logs, aalpha, palpha);
  score_softmax<<<Bb * Pp / 32, 512, 0, stream>>>(
      bias16, aftP_hi, aftP_lo, nodesP_hi, nodesP_lo, (float*)d_out);
}

// Round 10
// 372.962 us; speedup vs baseline: 1.8407x; 1.0054x over previous
//
#include <hip/hip_runtime.h>
#include <math.h>

#define Bb 32
#define Pp 1024
#define Nn 1024

typedef unsigned short u16;
typedef __bf16 bf16x8 __attribute__((ext_vector_type(8)));
typedef float f32x4 __attribute__((ext_vector_type(4)));
typedef u16 us8 __attribute__((ext_vector_type(8)));
typedef u16 us4 __attribute__((ext_vector_type(4)));

#define MFMA __builtin_amdgcn_mfma_f32_16x16x32_bf16

static constexpr float INV_SQRT_E = 0.08838834764831845f;  // 1/sqrt(128)

__device__ __forceinline__ bf16x8 asbf(us8 v) { return __builtin_bit_cast(bf16x8, v); }

// RTN split: x ~= hi + lo to ~2^-17 rel
__device__ __forceinline__ void bsplit(float x, u16& h, u16& l) {
  unsigned u = __float_as_uint(x);
  unsigned r = u + 0x7FFF + ((u >> 16) & 1);
  h = (u16)(r >> 16);
  float hf = __uint_as_float((unsigned)h << 16);
  float lof = x - hf;
  unsigned u2 = __float_as_uint(lof);
  unsigned r2 = u2 + 0x7FFF + ((u2 >> 16) & 1);
  l = (u16)(r2 >> 16);
}

// trunc split: x ~= hi + lo to ~2^-16 rel, cheap
__device__ __forceinline__ void tsplit(float x, u16& h, u16& l) {
  unsigned u = __float_as_uint(x);
  h = (u16)(u >> 16);
  float lof = x - __uint_as_float(u & 0xFFFF0000u);
  l = (u16)(__float_as_uint(lof) >> 16);
}

// exp(10*tanh(s)) with rcp instead of full divide (~1e-7 rel err)
__device__ __forceinline__ float exp10tanh(float s) {
  float ax = fabsf(s);
  float u = __expf(-2.0f * ax);                    // (0,1]
  float r = __builtin_amdgcn_rcpf(1.0f + u);
  float tt = fmaf(-2.0f * u, r, 1.0f);             // tanh(ax)
  tt = copysignf(tt, s);
  return __expf(10.0f * tt);
}

// ---------------- K0: transposed split weight planes ----------------
__global__ __launch_bounds__(256) void prep_weights(
    const float* __restrict__ Wq1, const float* __restrict__ Wq2,
    const float* __restrict__ Wql, const float* __restrict__ Wk,
    const float* __restrict__ Wv, u16* __restrict__ wcat_hi, u16* __restrict__ wcat_lo,
    u16* __restrict__ wkv_hi, u16* __restrict__ wkv_lo) {
  int t = threadIdx.x;
  if (blockIdx.x == 0) {
    for (int i = t; i < 128 * 384; i += 256) {
      int c = i / 384, k = i % 384;
      float v = (k < 128) ? Wq1[k * 128 + c]
                          : (k < 256) ? Wq2[(k - 128) * 128 + c] : Wql[(k - 256) * 128 + c];
      u16 h, l;
      bsplit(v, h, l);
      wcat_hi[i] = h;
      wcat_lo[i] = l;
    }
  } else {
    for (int i = t; i < 256 * 128; i += 256) {
      int c = i >> 7, k = i & 127;
      float v = (c < 128) ? Wk[k * 128 + c] : Wv[k * 128 + (c - 128)];
      u16 h, l;
      bsplit(v, h, l);
      wkv_hi[i] = h;
      wkv_lo[i] = l;
    }
  }
}

// ---------------- K1: k/v GEMM -> ekkP ([b][nch128][c256][8]) + nodesP ----------------
__global__ __launch_bounds__(256, 1) void kv_prep(
    const float* __restrict__ nodes, const u16* __restrict__ wkv_hi,
    const u16* __restrict__ wkv_lo, u16* __restrict__ ekkP_hi, u16* __restrict__ ekkP_lo,
    u16* __restrict__ nodesP_hi, u16* __restrict__ nodesP_lo) {
  __shared__ u16 a_hi[32 * 136], a_lo[32 * 136];
  __shared__ float kvbuf[32 * 264];
  const int t = threadIdx.x;
  const int xcd = blockIdx.x & 7, jj = blockIdx.x >> 3;
  const int b = xcd * 4 + (jj >> 5);
  const int n0 = (jj & 31) * 32;
  for (int i = t; i < 4096; i += 256) {
    int n = i >> 7, d = i & 127;
    float v = nodes[((long)(b * 1024 + n0 + n)) * 128 + d];
    u16 h, l;
    bsplit(v, h, l);
    a_hi[n * 136 + d] = h;
    a_lo[n * 136 + d] = l;
  }
  __syncthreads();
  const int lane = t & 63, w = t >> 6;
  const int lr = lane & 15, lg = lane >> 4;
  f32x4 acc0[2][4] = {}, acc1[2][4] = {};
#pragma unroll
  for (int ks = 0; ks < 4; ++ks) {
    us8 ah[2], al[2];
#pragma unroll
    for (int mt = 0; mt < 2; ++mt) {
      int ro = (lr + 16 * mt) * 136 + ks * 32 + lg * 8;
      ah[mt] = *(const us8*)&a_hi[ro];
      al[mt] = *(const us8*)&a_lo[ro];
    }
    us8 bh[4], bl[4];
#pragma unroll
    for (int cc = 0; cc < 4; ++cc) {
      long off = (long)((w * 4 + cc) * 16 + lr) * 128 + ks * 32 + lg * 8;
      bh[cc] = *(const us8*)&wkv_hi[off];
      bl[cc] = *(const us8*)&wkv_lo[off];
    }
#pragma unroll
    for (int mt = 0; mt < 2; ++mt)
#pragma unroll
      for (int cc = 0; cc < 4; ++cc) {
        acc0[mt][cc] = MFMA(asbf(ah[mt]), asbf(bh[cc]), acc0[mt][cc], 0, 0, 0);
        acc1[mt][cc] = MFMA(asbf(al[mt]), asbf(bh[cc]), acc1[mt][cc], 0, 0, 0);
        acc1[mt][cc] = MFMA(asbf(ah[mt]), asbf(bl[cc]), acc1[mt][cc], 0, 0, 0);
      }
  }
#pragma unroll
  for (int mt = 0; mt < 2; ++mt)
#pragma unroll
    for (int cc = 0; cc < 4; ++cc) {
      int c = (w * 4 + cc) * 16 + lr;
#pragma unroll
      for (int r = 0; r < 4; ++r)
        kvbuf[(lg * 4 + r + 16 * mt) * 264 + c] = acc0[mt][cc][r] + acc1[mt][cc][r];
    }
  __syncthreads();
#pragma unroll
  for (int jo = 0; jo < 4; ++jo) {
    int c = jo * 64 + (t & 63);
    int i4 = t >> 6;
    int kcol = (c < 128) ? c : (c - 128);
    us8 h8, l8;
#pragma unroll
    for (int jq = 0; jq < 8; ++jq) {
      int n = i4 * 8 + jq;
      float kv = kvbuf[n * 264 + kcol];
      float ek = __expf(kv);
      float val = (c < 128) ? ek * kvbuf[n * 264 + c + 128] : ek;
      u16 h, l;
      bsplit(val, h, l);
      h8[jq] = h;
      l8[jq] = l;
    }
    long o = (((long)b * 128 + (n0 >> 3) + i4) * 256 + c) * 8;
    *(us8*)&ekkP_hi[o] = h8;
    *(us8*)&ekkP_lo[o] = l8;
  }
  {
    int pl = t >> 7, r = t & 127;
    int dgrp = r >> 3, nb = r & 7;
    const u16* src = pl ? a_lo : a_hi;
    u16* dst = pl ? nodesP_lo : nodesP_hi;
#pragma unroll
    for (int i = 0; i < 4; ++i) {
      int n = nb + 8 * i;
      us8 v = *(const us8*)&src[n * 136 + dgrp * 8];
      *(us8*)&dst[(((long)(b * 16 + dgrp)) * 1024 + n0 + n) * 8] = v;
    }
  }
}

// ---------------- K2: q GEMM + sigmoid -> qsig f32 [32K][128] ----------------
__global__ __launch_bounds__(256) void qsig_prep(
    const float* __restrict__ q1m, const float* __restrict__ q2m,
    const float* __restrict__ lnm, const float* __restrict__ loadv,
    const float* __restrict__ leftv, const float* __restrict__ Wql,
    const u16* __restrict__ wcat_hi, const u16* __restrict__ wcat_lo,
    float* __restrict__ qsig) {
  const int t = threadIdx.x;
  const int lane = t & 63, w = t >> 6;
  const int lr = lane & 15, lg = lane >> 4;
  const long p0 = (long)blockIdx.x * 16;
  const long arow = p0 + lr;
  f32x4 qacc[2] = {};
#pragma unroll 2
  for (int s = 0; s < 12; ++s) {
    const float* __restrict__ src = (s < 4) ? q1m : (s < 8) ? q2m : lnm;
    long ao = arow * 128 + (s & 3) * 32 + lg * 8;
    float4 a0 = *(const float4*)&src[ao];
    float4 a1 = *(const float4*)&src[ao + 4];
    float av[8] = {a0.x, a0.y, a0.z, a0.w, a1.x, a1.y, a1.z, a1.w};
    us8 ah, al;
#pragma unroll
    for (int jq = 0; jq < 8; ++jq) {
      u16 hh, ll;
      tsplit(av[jq], hh, ll);
      ah[jq] = hh;
      al[jq] = ll;
    }
#pragma unroll
    for (int cf = 0; cf < 2; ++cf) {
      int c = w * 32 + cf * 16 + lr;
      us8 bh = *(const us8*)&wcat_hi[c * 384 + s * 32 + lg * 8];
      us8 bl = *(const us8*)&wcat_lo[c * 384 + s * 32 + lg * 8];
      qacc[cf] = MFMA(asbf(ah), asbf(bh), qacc[cf], 0, 0, 0);
      qacc[cf] = MFMA(asbf(al), asbf(bh), qacc[cf], 0, 0, 0);
      qacc[cf] = MFMA(asbf(ah), asbf(bl), qacc[cf], 0, 0, 0);
    }
  }
#pragma unroll
  for (int cf = 0; cf < 2; ++cf) {
    int c = w * 32 + cf * 16 + lr;
    float wl1 = Wql[128 * 128 + c], wl2 = Wql[129 * 128 + c];
#pragma unroll
    for (int r = 0; r < 4; ++r) {
      int row = lg * 4 + r;
      float qv = qacc[cf][r] + loadv[p0 + row] * wl1 + leftv[p0 + row] * wl2;
      qsig[(p0 + row) * 128 + c] = 1.0f / (1.0f + __expf(-qv));
    }
  }
}

// ---------------- K3: fused bias + [num|den] GEMM (32r x 256c x K1024) + AFT epilogue ----------------
// 1024 blocks (4/CU, 36KB LDS), 256 thr / 4 waves (wr=w>>1 row-group, wc=w&1 col-half).
__global__ __launch_bounds__(256, 3) void ndaft_gemm(
    const float* __restrict__ cdist, const float* __restrict__ ninf,
    const u16* __restrict__ ekkP_hi, const u16* __restrict__ ekkP_lo,
    const float* __restrict__ qsig, u16* __restrict__ aftP_hi,
    u16* __restrict__ aftP_lo, u16* __restrict__ bias16,
    const float* __restrict__ logs, const float* __restrict__ aal,
    const float* __restrict__ pal) {
  __shared__ u16 lds[18432];  // A: [pt2][pl2][oct4][pr16][8] = 2048 u16; B at 2048: [oct4][pl2][c256][8]
  const int t = threadIdx.x;
  const int lane = t & 63, w = t >> 6;
  const int lr = lane & 15, lg = lane >> 4;
  const int wr = w >> 1, wc = w & 1;
  const int xcd = blockIdx.x & 7, g = blockIdx.x >> 3;
  const int b = xcd * 4 + (g & 3);
  const int pt = g >> 2;  // 0..31, 32 rows each
  const long bp = (long)b * Pp + pt * 32;
  const float c1 = logs[0] * aal[0];
  const float c2 = logs[0] * pal[0];

  const int srow = (t < 128) ? (t >> 2) : 0;  // A-staging row 0..31 (first 2 waves only)
  const int soct = t & 3;
  const long arow = bp + srow;
  const long tbase = (arow >> 4) * 32768;
  const int pr = srow & 15, ptile = srow >> 4;

  float4 d0, d1, f0, f1;
  us8 bst[8];
  auto load_regs = [&](int s) {
    if (t < 128) {
      long ao = arow * 1024 + s * 32 + soct * 8;
      d0 = *(const float4*)&cdist[ao];
      d1 = *(const float4*)&cdist[ao + 4];
      f0 = *(const float4*)&ninf[ao];
      f1 = *(const float4*)&ninf[ao + 4];
    }
#pragma unroll
    for (int i = 0; i < 8; ++i) {
      int u = i * 256 + t;
      int oct = u >> 9, pl = (u >> 8) & 1, c = u & 255;
      const u16* bP = pl ? ekkP_lo : ekkP_hi;
      bst[i] = *(const us8*)&bP[(((long)b * 128 + s * 4 + oct) * 256 + c) * 8];
    }
  };

  us8 ebh, ebl;
  auto compute_eb = [&](int s) {
    if (t >= 128) return;
    float dv[8] = {d0.x, d0.y, d0.z, d0.w, d1.x, d1.y, d1.z, d1.w};
    float nv[8] = {f0.x, f0.y, f0.z, f0.w, f1.x, f1.y, f1.z, f1.w};
    us8 q8;
#pragma unroll
    for (int jq = 0; jq < 8; ++jq) {
      float e = __expf(fmaf(-c1, dv[jq], nv[jq]));
      u16 h, l;
      tsplit(e, h, l);
      ebh[jq] = h;
      ebl[jq] = l;
      float x = fminf(fmaxf(c2 * dv[jq], 0.f), 15.999f);
      q8[jq] = (nv[jq] < -1e5f) ? (u16)0xFFFF : (u16)(x * 4096.f + 0.5f);
    }
    *(us8*)&bias16[tbase + ((s * 4 + soct) * 16 + pr) * 8] = q8;
  };

  auto write_lds = [&]() {
    if (t < 128) {
      *(us8*)&lds[((ptile * 2 + 0) * 4 + soct) * 128 + pr * 8] = ebh;
      *(us8*)&lds[((ptile * 2 + 1) * 4 + soct) * 128 + pr * 8] = ebl;
    }
#pragma unroll
    for (int i = 0; i < 8; ++i) {
      int u = i * 256 + t;
      int oct = u >> 9, pl = (u >> 8) & 1, c = u & 255;
      *(us8*)&lds[2048 + ((oct * 2 + pl) * 256 + c) * 8] = bst[i];
    }
  };

  f32x4 acc[8] = {};
  load_regs(0);
  for (int s = 0; s < 32; ++s) {
    compute_eb(s);
    __syncthreads();  // prior stage's LDS reads complete
    write_lds();
    __syncthreads();
    if (s < 31) load_regs(s + 1);  // in flight under MFMA
    us8 ah = *(const us8*)&lds[((wr * 2 + 0) * 4 + lg) * 128 + lr * 8];
    us8 al = *(const us8*)&lds[((wr * 2 + 1) * 4 + lg) * 128 + lr * 8];
#pragma unroll
    for (int ct = 0; ct < 8; ++ct) {
      int c = (ct < 4) ? (wc * 64 + ct * 16 + lr) : (128 + wc * 64 + (ct - 4) * 16 + lr);
      us8 bh = *(const us8*)&lds[2048 + ((lg * 2 + 0) * 256 + c) * 8];
      us8 bl = *(const us8*)&lds[2048 + ((lg * 2 + 1) * 256 + c) * 8];
      acc[ct] = MFMA(asbf(ah), asbf(bh), acc[ct], 0, 0, 0);
      acc[ct] = MFMA(asbf(al), asbf(bh), acc[ct], 0, 0, 0);
      acc[ct] = MFMA(asbf(ah), asbf(bl), acc[ct], 0, 0, 0);
    }
  }
  // epilogue: aft = sig * num * rcp(den+eps) -> split bf16, packed aftP
#pragma unroll
  for (int ct = 0; ct < 4; ++ct) {
    int cn = wc * 64 + ct * 16 + lr;
    int nc = cn >> 3, jq = cn & 7;
#pragma unroll
    for (int r = 0; r < 4; ++r) {
      long gr = bp + wr * 16 + lg * 4 + r;
      float sig = qsig[gr * 128 + cn];
      float aftv = sig * acc[ct][r] * __builtin_amdgcn_rcpf(acc[ct + 4][r] + 1e-20f);
      u16 h, l;
      bsplit(aftv, h, l);
      long idx = (gr >> 4) * 2048 + (nc * 16 + (gr & 15)) * 8 + jq;
      aftP_hi[idx] = h;
      aftP_lo[idx] = l;
    }
  }
}

// ---------------- K4: score GEMM (transposed) + tanh-clip softmax ----------------
// 2048 blocks x 256 thr: 16 rows, 4 waves (one n-quarter each). Depth-2 B prefetch ring.
// bias from u16 fixed-point plane in d_out (first 32KB of this tile's 64KB region);
// direct float4 stores (lane holds 4 consecutive n in transposed layout).
__global__ __launch_bounds__(256, 4) void score_softmax(
    const u16* bias16, const u16* __restrict__ aftP_hi, const u16* __restrict__ aftP_lo,
    const u16* __restrict__ nodesP_hi, const u16* __restrict__ nodesP_lo,
    float* out) {
  __shared__ float psum[16 * 4];
  __shared__ float invb[16];
  const int t = threadIdx.x;
  const int lane = t & 63, w = t >> 6;  // w = n-quarter
  const int lr = lane & 15, lg = lane >> 4;
  const int xcd = blockIdx.x & 7, j = blockIdx.x >> 3;  // j 0..255
  const int b = xcd * 4 + (j >> 6);
  const int tl = j & 63;
  const int p0 = tl * 16;
  const long bp = (long)b * Pp + p0;
  const int tile = b * 64 + tl;

  // P4: transposed score GEMM: lane holds (n = w*256+cf*16+lg*4+r, p = lr)
  f32x4 sacc[16] = {};
#pragma unroll
  for (int ks = 0; ks < 4; ++ks) {
    long aoff = (long)tile * 2048 + ((long)((ks * 4 + lg) * 16 + lr)) * 8;
    us8 ah = *(const us8*)&aftP_hi[aoff];
    us8 al = *(const us8*)&aftP_lo[aoff];
    long nb = ((long)(b * 16 + ks * 4 + lg)) * 1024;
    auto bld = [&](int cf, us8& bh, us8& bl) {
      long o = (nb + w * 256 + cf * 16 + lr) * 8;
      bh = *(const us8*)&nodesP_hi[o];
      bl = *(const us8*)&nodesP_lo[o];
    };
    us8 bh0, bl0, bh1, bl1;
    bld(0, bh0, bl0);
    bld(1, bh1, bl1);
#pragma unroll
    for (int cf = 0; cf < 16; ++cf) {
      us8 nh = bh1, nl = bl1;
      if (cf < 14) bld(cf + 2, nh, nl);  // issue 2 iterations ahead
      sacc[cf] = MFMA(asbf(bh0), asbf(ah), sacc[cf], 0, 0, 0);
      sacc[cf] = MFMA(asbf(bl0), asbf(ah), sacc[cf], 0, 0, 0);
      sacc[cf] = MFMA(asbf(bh0), asbf(al), sacc[cf], 0, 0, 0);
      bh0 = bh1; bl0 = bl1; bh1 = nh; bl1 = nl;
    }
  }

  // P5a: fixed-point bias + tanh-clip + exp (rcp-based)
  const long btile = (long)tile * 32768;
  float rs = 0.f;
#pragma unroll
  for (int cf = 0; cf < 16; ++cf) {
    int nc = w * 32 + cf * 2 + (lg >> 1);
    int j0 = (lg & 1) * 4;
    us4 q4 = *(const us4*)&bias16[btile + (nc * 16 + lr) * 8 + j0];
#pragma unroll
    for (int r = 0; r < 4; ++r) {
      u16 qv = q4[r];
      float sv = fmaf(sacc[cf][r], INV_SQRT_E, (float)qv * -2.44140625e-4f);
      float e = exp10tanh(sv);
      e = (qv == (u16)0xFFFF) ? 0.f : e;
      sacc[cf][r] = e;
      rs += e;
    }
  }
  // P5b: reduce over lg (xor 16,32) then across the 4 waves via psum
  rs += __shfl_xor(rs, 16);
  rs += __shfl_xor(rs, 32);
  if (lane < 16) psum[lr * 4 + w] = rs;
  __syncthreads();
  if (t < 16)
    invb[t] = 1.0f / (psum[t * 4] + psum[t * 4 + 1] + psum[t * 4 + 2] + psum[t * 4 + 3]);
  __syncthreads();

  // P5c: normalize + direct float4 stores (4 consecutive n per lane)
  const float inv = invb[lr];
  const long ro = (bp + lr) * (long)Nn + w * 256;
#pragma unroll
  for (int cf = 0; cf < 16; ++cf) {
    float4 v;
    v.x = sacc[cf][0] * inv;
    v.y = sacc[cf][1] * inv;
    v.z = sacc[cf][2] * inv;
    v.w = sacc[cf][3] * inv;
    *(float4*)&out[ro + cf * 16 + lg * 4] = v;
  }
}

extern "C" void kernel_launch(void* const* d_in, const int* in_sizes, int n_in,
                              void* d_out, int out_size, void* d_ws, size_t ws_size,
                              hipStream_t stream) {
  const float* nodes = (const float*)d_in[0];
  const float* q1m = (const float*)d_in[1];
  const float* q2m = (const float*)d_in[2];
  const float* lnm = (const float*)d_in[3];
  const float* loadv = (const float*)d_in[4];
  const float* leftv = (const float*)d_in[5];
  const float* cdist = (const float*)d_in[6];
  const float* logs = (const float*)d_in[7];
  const float* ninf = (const float*)d_in[8];
  const float* Wq1 = (const float*)d_in[9];
  const float* Wq2 = (const float*)d_in[10];
  const float* Wql = (const float*)d_in[11];
  const float* Wk = (const float*)d_in[12];
  const float* Wv = (const float*)d_in[13];
  const float* aalpha = (const float*)d_in[14];
  const float* palpha = (const float*)d_in[15];

  char* ws = (char*)d_ws;
  u16* ekkP_hi = (u16*)ws;                      // 16 MB
  u16* ekkP_lo = (u16*)(ws + (16ul << 20));     // 16 MB
  u16* nodesP_hi = (u16*)(ws + (32ul << 20));   // 8 MB
  u16* nodesP_lo = (u16*)(ws + (40ul << 20));   // 8 MB
  float* qsig = (float*)(ws + (48ul << 20));    // 16 MB
  u16* aftP_hi = (u16*)(ws + (64ul << 20));     // 8 MB
  u16* aftP_lo = (u16*)(ws + (72ul << 20));     // 8 MB
  u16* wcat_hi = (u16*)(ws + (80ul << 20));
  u16* wcat_lo = wcat_hi + 128 * 384;
  u16* wkv_hi = wcat_lo + 128 * 384;
  u16* wkv_lo = wkv_hi + 256 * 128;
  // bias16 lives in the first 32KB of each 64KB out-tile region; score reads
  // its own tile's bias before overwriting the region with probs.
  u16* bias16 = (u16*)d_out;

  prep_weights<<<2, 256, 0, stream>>>(Wq1, Wq2, Wql, Wk, Wv, wcat_hi, wcat_lo, wkv_hi, wkv_lo);
  kv_prep<<<Bb * Nn / 32, 256, 0, stream>>>(nodes, wkv_hi, wkv_lo, ekkP_hi, ekkP_lo,
                                            nodesP_hi, nodesP_lo);
  qsig_prep<<<2048, 256, 0, stream>>>(q1m, q2m, lnm, loadv, leftv, Wql, wcat_hi, wcat_lo,
                                      qsig);
  ndaft_gemm<<<1024, 256, 0, stream>>>(cdist, ninf, ekkP_hi, ekkP_lo, qsig, aftP_hi,
                                       aftP_lo, bias16, logs, aalpha, palpha);
  score_softmax<<<Bb * Pp / 16, 256, 0, stream>>>(
      bias16, aftP_hi, aftP_lo, nodesP_hi, nodesP_lo, (float*)d_out);
}

// Round 11
// 363.493 us; speedup vs baseline: 1.8887x; 1.0260x over previous
//
#include <hip/hip_runtime.h>
#include <math.h>

#define Bb 32
#define Pp 1024
#define Nn 1024

typedef unsigned short u16;
typedef __bf16 bf16x8 __attribute__((ext_vector_type(8)));
typedef float f32x4 __attribute__((ext_vector_type(4)));
typedef u16 us8 __attribute__((ext_vector_type(8)));
typedef u16 us4 __attribute__((ext_vector_type(4)));

#define MFMA __builtin_amdgcn_mfma_f32_16x16x32_bf16

static constexpr float INV_SQRT_E = 0.08838834764831845f;  // 1/sqrt(128)

__device__ __forceinline__ bf16x8 asbf(us8 v) { return __builtin_bit_cast(bf16x8, v); }

// RTN split: x ~= hi + lo to ~2^-17 rel
__device__ __forceinline__ void bsplit(float x, u16& h, u16& l) {
  unsigned u = __float_as_uint(x);
  unsigned r = u + 0x7FFF + ((u >> 16) & 1);
  h = (u16)(r >> 16);
  float hf = __uint_as_float((unsigned)h << 16);
  float lof = x - hf;
  unsigned u2 = __float_as_uint(lof);
  unsigned r2 = u2 + 0x7FFF + ((u2 >> 16) & 1);
  l = (u16)(r2 >> 16);
}

// trunc split: x ~= hi + lo to ~2^-16 rel, cheap
__device__ __forceinline__ void tsplit(float x, u16& h, u16& l) {
  unsigned u = __float_as_uint(x);
  h = (u16)(u >> 16);
  float lof = x - __uint_as_float(u & 0xFFFF0000u);
  l = (u16)(__float_as_uint(lof) >> 16);
}

// exp(10*tanh(s)) with rcp instead of full divide (~1e-7 rel err)
__device__ __forceinline__ float exp10tanh(float s) {
  float ax = fabsf(s);
  float u = __expf(-2.0f * ax);                    // (0,1]
  float r = __builtin_amdgcn_rcpf(1.0f + u);
  float tt = fmaf(-2.0f * u, r, 1.0f);             // tanh(ax)
  tt = copysignf(tt, s);
  return __expf(10.0f * tt);
}

// ---------------- K0: transposed split weight planes ----------------
__global__ __launch_bounds__(256) void prep_weights(
    const float* __restrict__ Wq1, const float* __restrict__ Wq2,
    const float* __restrict__ Wql, const float* __restrict__ Wk,
    const float* __restrict__ Wv, u16* __restrict__ wcat_hi, u16* __restrict__ wcat_lo,
    u16* __restrict__ wkv_hi, u16* __restrict__ wkv_lo) {
  int t = threadIdx.x;
  if (blockIdx.x == 0) {
    for (int i = t; i < 128 * 384; i += 256) {
      int c = i / 384, k = i % 384;
      float v = (k < 128) ? Wq1[k * 128 + c]
                          : (k < 256) ? Wq2[(k - 128) * 128 + c] : Wql[(k - 256) * 128 + c];
      u16 h, l;
      bsplit(v, h, l);
      wcat_hi[i] = h;
      wcat_lo[i] = l;
    }
  } else {
    for (int i = t; i < 256 * 128; i += 256) {
      int c = i >> 7, k = i & 127;
      float v = (c < 128) ? Wk[k * 128 + c] : Wv[k * 128 + (c - 128)];
      u16 h, l;
      bsplit(v, h, l);
      wkv_hi[i] = h;
      wkv_lo[i] = l;
    }
  }
}

// ---------------- K1: k/v GEMM -> ekkP ([b][nch128][c256][8]) + nodesP ----------------
__global__ __launch_bounds__(256, 1) void kv_prep(
    const float* __restrict__ nodes, const u16* __restrict__ wkv_hi,
    const u16* __restrict__ wkv_lo, u16* __restrict__ ekkP_hi, u16* __restrict__ ekkP_lo,
    u16* __restrict__ nodesP_hi, u16* __restrict__ nodesP_lo) {
  __shared__ u16 a_hi[32 * 136], a_lo[32 * 136];
  __shared__ float kvbuf[32 * 264];
  const int t = threadIdx.x;
  const int xcd = blockIdx.x & 7, jj = blockIdx.x >> 3;
  const int b = xcd * 4 + (jj >> 5);
  const int n0 = (jj & 31) * 32;
  for (int i = t; i < 4096; i += 256) {
    int n = i >> 7, d = i & 127;
    float v = nodes[((long)(b * 1024 + n0 + n)) * 128 + d];
    u16 h, l;
    bsplit(v, h, l);
    a_hi[n * 136 + d] = h;
    a_lo[n * 136 + d] = l;
  }
  __syncthreads();
  const int lane = t & 63, w = t >> 6;
  const int lr = lane & 15, lg = lane >> 4;
  f32x4 acc0[2][4] = {}, acc1[2][4] = {};
#pragma unroll
  for (int ks = 0; ks < 4; ++ks) {
    us8 ah[2], al[2];
#pragma unroll
    for (int mt = 0; mt < 2; ++mt) {
      int ro = (lr + 16 * mt) * 136 + ks * 32 + lg * 8;
      ah[mt] = *(const us8*)&a_hi[ro];
      al[mt] = *(const us8*)&a_lo[ro];
    }
    us8 bh[4], bl[4];
#pragma unroll
    for (int cc = 0; cc < 4; ++cc) {
      long off = (long)((w * 4 + cc) * 16 + lr) * 128 + ks * 32 + lg * 8;
      bh[cc] = *(const us8*)&wkv_hi[off];
      bl[cc] = *(const us8*)&wkv_lo[off];
    }
#pragma unroll
    for (int mt = 0; mt < 2; ++mt)
#pragma unroll
      for (int cc = 0; cc < 4; ++cc) {
        acc0[mt][cc] = MFMA(asbf(ah[mt]), asbf(bh[cc]), acc0[mt][cc], 0, 0, 0);
        acc1[mt][cc] = MFMA(asbf(al[mt]), asbf(bh[cc]), acc1[mt][cc], 0, 0, 0);
        acc1[mt][cc] = MFMA(asbf(ah[mt]), asbf(bl[cc]), acc1[mt][cc], 0, 0, 0);
      }
  }
#pragma unroll
  for (int mt = 0; mt < 2; ++mt)
#pragma unroll
    for (int cc = 0; cc < 4; ++cc) {
      int c = (w * 4 + cc) * 16 + lr;
#pragma unroll
      for (int r = 0; r < 4; ++r)
        kvbuf[(lg * 4 + r + 16 * mt) * 264 + c] = acc0[mt][cc][r] + acc1[mt][cc][r];
    }
  __syncthreads();
#pragma unroll
  for (int jo = 0; jo < 4; ++jo) {
    int c = jo * 64 + (t & 63);
    int i4 = t >> 6;
    int kcol = (c < 128) ? c : (c - 128);
    us8 h8, l8;
#pragma unroll
    for (int jq = 0; jq < 8; ++jq) {
      int n = i4 * 8 + jq;
      float kv = kvbuf[n * 264 + kcol];
      float ek = __expf(kv);
      float val = (c < 128) ? ek * kvbuf[n * 264 + c + 128] : ek;
      u16 h, l;
      bsplit(val, h, l);
      h8[jq] = h;
      l8[jq] = l;
    }
    long o = (((long)b * 128 + (n0 >> 3) + i4) * 256 + c) * 8;
    *(us8*)&ekkP_hi[o] = h8;
    *(us8*)&ekkP_lo[o] = l8;
  }
  {
    int pl = t >> 7, r = t & 127;
    int dgrp = r >> 3, nb = r & 7;
    const u16* src = pl ? a_lo : a_hi;
    u16* dst = pl ? nodesP_lo : nodesP_hi;
#pragma unroll
    for (int i = 0; i < 4; ++i) {
      int n = nb + 8 * i;
      us8 v = *(const us8*)&src[n * 136 + dgrp * 8];
      *(us8*)&dst[(((long)(b * 16 + dgrp)) * 1024 + n0 + n) * 8] = v;
    }
  }
}

// ---------------- K2: q GEMM + sigmoid -> qsig f32 [32K][128] ----------------
__global__ __launch_bounds__(256) void qsig_prep(
    const float* __restrict__ q1m, const float* __restrict__ q2m,
    const float* __restrict__ lnm, const float* __restrict__ loadv,
    const float* __restrict__ leftv, const float* __restrict__ Wql,
    const u16* __restrict__ wcat_hi, const u16* __restrict__ wcat_lo,
    float* __restrict__ qsig) {
  const int t = threadIdx.x;
  const int lane = t & 63, w = t >> 6;
  const int lr = lane & 15, lg = lane >> 4;
  const long p0 = (long)blockIdx.x * 16;
  const long arow = p0 + lr;
  f32x4 qacc[2] = {};
#pragma unroll 2
  for (int s = 0; s < 12; ++s) {
    const float* __restrict__ src = (s < 4) ? q1m : (s < 8) ? q2m : lnm;
    long ao = arow * 128 + (s & 3) * 32 + lg * 8;
    float4 a0 = *(const float4*)&src[ao];
    float4 a1 = *(const float4*)&src[ao + 4];
    float av[8] = {a0.x, a0.y, a0.z, a0.w, a1.x, a1.y, a1.z, a1.w};
    us8 ah, al;
#pragma unroll
    for (int jq = 0; jq < 8; ++jq) {
      u16 hh, ll;
      tsplit(av[jq], hh, ll);
      ah[jq] = hh;
      al[jq] = ll;
    }
#pragma unroll
    for (int cf = 0; cf < 2; ++cf) {
      int c = w * 32 + cf * 16 + lr;
      us8 bh = *(const us8*)&wcat_hi[c * 384 + s * 32 + lg * 8];
      us8 bl = *(const us8*)&wcat_lo[c * 384 + s * 32 + lg * 8];
      qacc[cf] = MFMA(asbf(ah), asbf(bh), qacc[cf], 0, 0, 0);
      qacc[cf] = MFMA(asbf(al), asbf(bh), qacc[cf], 0, 0, 0);
      qacc[cf] = MFMA(asbf(ah), asbf(bl), qacc[cf], 0, 0, 0);
    }
  }
#pragma unroll
  for (int cf = 0; cf < 2; ++cf) {
    int c = w * 32 + cf * 16 + lr;
    float wl1 = Wql[128 * 128 + c], wl2 = Wql[129 * 128 + c];
#pragma unroll
    for (int r = 0; r < 4; ++r) {
      int row = lg * 4 + r;
      float qv = qacc[cf][r] + loadv[p0 + row] * wl1 + leftv[p0 + row] * wl2;
      qsig[(p0 + row) * 128 + c] = 1.0f / (1.0f + __expf(-qv));
    }
  }
}

// ---------------- K3: fused bias + [num|den] GEMM (128r x 256c x K1024) + AFT epilogue ----------------
// 256 blocks (1/CU), 512 thr / 8 waves. Wave tile: 64 rows x (32 num + 32 den paired cols)
// -> 48 MFMA per 16 KB LDS reads. A-layout oct-padded (136 u16) to kill write bank conflicts.
__global__ __launch_bounds__(512, 2) void ndaft_gemm(
    const float* __restrict__ cdist, const float* __restrict__ ninf,
    const u16* __restrict__ ekkP_hi, const u16* __restrict__ ekkP_lo,
    const float* __restrict__ qsig, u16* __restrict__ aftP_hi,
    u16* __restrict__ aftP_lo, u16* __restrict__ bias16,
    const float* __restrict__ logs, const float* __restrict__ aal,
    const float* __restrict__ pal) {
  // A: [ptile8][pl2][oct4][136] u16 = 8704 ; B at 8704: hi[oct4][c256][8]=8192, lo +8192
  __shared__ u16 lds[25088];  // 50176 B
  const int t = threadIdx.x;
  const int lane = t & 63, w = t >> 6;
  const int lr = lane & 15, lg = lane >> 4;
  const int wr = w >> 2, wc = w & 3;  // wave: rows wr*64.., num cols wc*32.., den 128+wc*32..
  const int xcd = blockIdx.x & 7, j = blockIdx.x >> 3;  // j 0..31
  const int b = xcd * 4 + (j & 3);
  const int pt = j >> 2;  // 0..7 (128 rows each)
  const long bp = (long)b * Pp + pt * 128;
  const float c1 = logs[0] * aal[0];
  const float c2 = logs[0] * pal[0];

  const int srow = t >> 2, soct = t & 3;  // A staging: 128 rows x 4 K-octs
  const long arow = bp + srow;
  const long tbase = (arow >> 4) * 32768;
  const int spr = srow & 15, sptile = srow >> 4;
  const long bsrc = (long)b * 128 * 2048;  // u16 idx of this batch's ekkP panel

  float4 d0, d1, f0, f1;
  us8 bst[4];
  auto load_regs = [&](int s) {
    long ao = arow * 1024 + s * 32 + soct * 8;
    d0 = *(const float4*)&cdist[ao];
    d1 = *(const float4*)&cdist[ao + 4];
    f0 = *(const float4*)&ninf[ao];
    f1 = *(const float4*)&ninf[ao + 4];
    long sb = bsrc + (long)s * 8192;  // stage panel: 4 octs x 2048 u16, contiguous
#pragma unroll
    for (int i = 0; i < 2; ++i) {
      bst[i] = *(const us8*)&ekkP_hi[sb + (i * 512 + t) * 8];
      bst[i + 2] = *(const us8*)&ekkP_lo[sb + (i * 512 + t) * 8];
    }
  };

  us8 ebh, ebl;
  auto compute_eb = [&](int s) {
    float dv[8] = {d0.x, d0.y, d0.z, d0.w, d1.x, d1.y, d1.z, d1.w};
    float nv[8] = {f0.x, f0.y, f0.z, f0.w, f1.x, f1.y, f1.z, f1.w};
    us8 q8;
#pragma unroll
    for (int jq = 0; jq < 8; ++jq) {
      float e = __expf(fmaf(-c1, dv[jq], nv[jq]));
      u16 h, l;
      tsplit(e, h, l);
      ebh[jq] = h;
      ebl[jq] = l;
      float x = fminf(fmaxf(c2 * dv[jq], 0.f), 15.999f);
      q8[jq] = (nv[jq] < -1e5f) ? (u16)0xFFFF : (u16)(x * 4096.f + 0.5f);
    }
    *(us8*)&bias16[tbase + ((s * 4 + soct) * 16 + spr) * 8] = q8;
  };

  auto write_lds = [&]() {
    *(us8*)&lds[((sptile * 2 + 0) * 4 + soct) * 136 + spr * 8] = ebh;
    *(us8*)&lds[((sptile * 2 + 1) * 4 + soct) * 136 + spr * 8] = ebl;
#pragma unroll
    for (int i = 0; i < 2; ++i) {
      *(us8*)&lds[8704 + (i * 512 + t) * 8] = bst[i];
      *(us8*)&lds[8704 + 8192 + (i * 512 + t) * 8] = bst[i + 2];
    }
  };

  f32x4 acc[4][4] = {};
  load_regs(0);
  for (int s = 0; s < 32; ++s) {
    compute_eb(s);
    __syncthreads();  // prior stage's LDS reads complete
    write_lds();
    __syncthreads();  // staged data visible
    if (s < 31) load_regs(s + 1);  // in flight under MFMA
    us8 ah[4], al[4];
#pragma unroll
    for (int mt = 0; mt < 4; ++mt) {
      int ptl = wr * 4 + mt;
      ah[mt] = *(const us8*)&lds[((ptl * 2 + 0) * 4 + lg) * 136 + lr * 8];
      al[mt] = *(const us8*)&lds[((ptl * 2 + 1) * 4 + lg) * 136 + lr * 8];
    }
#pragma unroll
    for (int ct = 0; ct < 4; ++ct) {
      int c = (ct < 2) ? (wc * 32 + ct * 16 + lr) : (96 + wc * 32 + ct * 16 + lr);
      us8 bh = *(const us8*)&lds[8704 + lg * 2048 + c * 8];
      us8 bl = *(const us8*)&lds[8704 + 8192 + lg * 2048 + c * 8];
#pragma unroll
      for (int mt = 0; mt < 4; ++mt) {
        acc[mt][ct] = MFMA(asbf(ah[mt]), asbf(bh), acc[mt][ct], 0, 0, 0);
        acc[mt][ct] = MFMA(asbf(al[mt]), asbf(bh), acc[mt][ct], 0, 0, 0);
        acc[mt][ct] = MFMA(asbf(ah[mt]), asbf(bl), acc[mt][ct], 0, 0, 0);
      }
    }
  }
  // epilogue: aft = sig * num * rcp(den+eps) -> split bf16, packed aftP
#pragma unroll
  for (int mt = 0; mt < 4; ++mt)
#pragma unroll
    for (int ct = 0; ct < 2; ++ct) {
      int cn = wc * 32 + ct * 16 + lr;
      int nc = cn >> 3, jq = cn & 7;
#pragma unroll
      for (int r = 0; r < 4; ++r) {
        long gr = bp + wr * 64 + mt * 16 + lg * 4 + r;
        float sig = qsig[gr * 128 + cn];
        float aftv = sig * acc[mt][ct][r] * __builtin_amdgcn_rcpf(acc[mt][ct + 2][r] + 1e-20f);
        u16 h, l;
        bsplit(aftv, h, l);
        long idx = (gr >> 4) * 2048 + (nc * 16 + (gr & 15)) * 8 + jq;
        aftP_hi[idx] = h;
        aftP_lo[idx] = l;
      }
    }
}

// ---------------- K4: score GEMM (transposed) + tanh-clip softmax ----------------
// 2048 blocks x 256 thr: 16 rows, 4 waves (one n-quarter each). Depth-2 B prefetch ring.
__global__ __launch_bounds__(256, 4) void score_softmax(
    const u16* bias16, const u16* __restrict__ aftP_hi, const u16* __restrict__ aftP_lo,
    const u16* __restrict__ nodesP_hi, const u16* __restrict__ nodesP_lo,
    float* out) {
  __shared__ float psum[16 * 4];
  __shared__ float invb[16];
  const int t = threadIdx.x;
  const int lane = t & 63, w = t >> 6;  // w = n-quarter
  const int lr = lane & 15, lg = lane >> 4;
  const int xcd = blockIdx.x & 7, j = blockIdx.x >> 3;  // j 0..255
  const int b = xcd * 4 + (j >> 6);
  const int tl = j & 63;
  const int p0 = tl * 16;
  const long bp = (long)b * Pp + p0;
  const int tile = b * 64 + tl;

  f32x4 sacc[16] = {};
#pragma unroll
  for (int ks = 0; ks < 4; ++ks) {
    long aoff = (long)tile * 2048 + ((long)((ks * 4 + lg) * 16 + lr)) * 8;
    us8 ah = *(const us8*)&aftP_hi[aoff];
    us8 al = *(const us8*)&aftP_lo[aoff];
    long nb = ((long)(b * 16 + ks * 4 + lg)) * 1024;
    auto bld = [&](int cf, us8& bh, us8& bl) {
      long o = (nb + w * 256 + cf * 16 + lr) * 8;
      bh = *(const us8*)&nodesP_hi[o];
      bl = *(const us8*)&nodesP_lo[o];
    };
    us8 bh0, bl0, bh1, bl1;
    bld(0, bh0, bl0);
    bld(1, bh1, bl1);
#pragma unroll
    for (int cf = 0; cf < 16; ++cf) {
      us8 nh = bh1, nl = bl1;
      if (cf < 14) bld(cf + 2, nh, nl);  // issue 2 iterations ahead
      sacc[cf] = MFMA(asbf(bh0), asbf(ah), sacc[cf], 0, 0, 0);
      sacc[cf] = MFMA(asbf(bl0), asbf(ah), sacc[cf], 0, 0, 0);
      sacc[cf] = MFMA(asbf(bh0), asbf(al), sacc[cf], 0, 0, 0);
      bh0 = bh1; bl0 = bl1; bh1 = nh; bl1 = nl;
    }
  }

  const long btile = (long)tile * 32768;
  float rs = 0.f;
#pragma unroll
  for (int cf = 0; cf < 16; ++cf) {
    int nc = w * 32 + cf * 2 + (lg >> 1);
    int j0 = (lg & 1) * 4;
    us4 q4 = *(const us4*)&bias16[btile + (nc * 16 + lr) * 8 + j0];
#pragma unroll
    for (int r = 0; r < 4; ++r) {
      u16 qv = q4[r];
      float sv = fmaf(sacc[cf][r], INV_SQRT_E, (float)qv * -2.44140625e-4f);
      float e = exp10tanh(sv);
      e = (qv == (u16)0xFFFF) ? 0.f : e;
      sacc[cf][r] = e;
      rs += e;
    }
  }
  rs += __shfl_xor(rs, 16);
  rs += __shfl_xor(rs, 32);
  if (lane < 16) psum[lr * 4 + w] = rs;
  __syncthreads();
  if (t < 16)
    invb[t] = 1.0f / (psum[t * 4] + psum[t * 4 + 1] + psum[t * 4 + 2] + psum[t * 4 + 3]);
  __syncthreads();

  const float inv = invb[lr];
  const long ro = (bp + lr) * (long)Nn + w * 256;
#pragma unroll
  for (int cf = 0; cf < 16; ++cf) {
    float4 v;
    v.x = sacc[cf][0] * inv;
    v.y = sacc[cf][1] * inv;
    v.z = sacc[cf][2] * inv;
    v.w = sacc[cf][3] * inv;
    *(float4*)&out[ro + cf * 16 + lg * 4] = v;
  }
}

extern "C" void kernel_launch(void* const* d_in, const int* in_sizes, int n_in,
                              void* d_out, int out_size, void* d_ws, size_t ws_size,
                              hipStream_t stream) {
  const float* nodes = (const float*)d_in[0];
  const float* q1m = (const float*)d_in[1];
  const float* q2m = (const float*)d_in[2];
  const float* lnm = (const float*)d_in[3];
  const float* loadv = (const float*)d_in[4];
  const float* leftv = (const float*)d_in[5];
  const float* cdist = (const float*)d_in[6];
  const float* logs = (const float*)d_in[7];
  const float* ninf = (const float*)d_in[8];
  const float* Wq1 = (const float*)d_in[9];
  const float* Wq2 = (const float*)d_in[10];
  const float* Wql = (const float*)d_in[11];
  const float* Wk = (const float*)d_in[12];
  const float* Wv = (const float*)d_in[13];
  const float* aalpha = (const float*)d_in[14];
  const float* palpha = (const float*)d_in[15];

  char* ws = (char*)d_ws;
  u16* ekkP_hi = (u16*)ws;                      // 16 MB
  u16* ekkP_lo = (u16*)(ws + (16ul << 20));     // 16 MB
  u16* nodesP_hi = (u16*)(ws + (32ul << 20));   // 8 MB
  u16* nodesP_lo = (u16*)(ws + (40ul << 20));   // 8 MB
  float* qsig = (float*)(ws + (48ul << 20));    // 16 MB
  u16* aftP_hi = (u16*)(ws + (64ul << 20));     // 8 MB
  u16* aftP_lo = (u16*)(ws + (72ul << 20));     // 8 MB
  u16* wcat_hi = (u16*)(ws + (80ul << 20));
  u16* wcat_lo = wcat_hi + 128 * 384;
  u16* wkv_hi = wcat_lo + 128 * 384;
  u16* wkv_lo = wkv_hi + 256 * 128;
  u16* bias16 = (u16*)d_out;  // first 32KB of each 64KB out-tile; read-then-overwritten

  prep_weights<<<2, 256, 0, stream>>>(Wq1, Wq2, Wql, Wk, Wv, wcat_hi, wcat_lo, wkv_hi, wkv_lo);
  kv_prep<<<Bb * Nn / 32, 256, 0, stream>>>(nodes, wkv_hi, wkv_lo, ekkP_hi, ekkP_lo,
                                            nodesP_hi, nodesP_lo);
  qsig_prep<<<2048, 256, 0, stream>>>(q1m, q2m, lnm, loadv, leftv, Wql, wcat_hi, wcat_lo,
                                      qsig);
  ndaft_gemm<<<256, 512, 0, stream>>>(cdist, ninf, ekkP_hi, ekkP_lo, qsig, aftP_hi,
                                      aftP_lo, bias16, logs, aalpha, palpha);
  score_softmax<<<Bb * Pp / 16, 256, 0, stream>>>(
      bias16, aftP_hi, aftP_lo, nodesP_hi, nodesP_lo, (float*)d_out);
}

// Round 12
// 357.888 us; speedup vs baseline: 1.9183x; 1.0157x over previous
//
#include <hip/hip_runtime.h>
#include <math.h>

#define Bb 32
#define Pp 1024
#define Nn 1024

typedef unsigned short u16;
typedef __bf16 bf16x8 __attribute__((ext_vector_type(8)));
typedef float f32x4 __attribute__((ext_vector_type(4)));
typedef u16 us8 __attribute__((ext_vector_type(8)));
typedef u16 us4 __attribute__((ext_vector_type(4)));

#define MFMA __builtin_amdgcn_mfma_f32_16x16x32_bf16

static constexpr float INV_SQRT_E = 0.08838834764831845f;  // 1/sqrt(128)

__device__ __forceinline__ bf16x8 asbf(us8 v) { return __builtin_bit_cast(bf16x8, v); }

// RTN split: x ~= hi + lo to ~2^-17 rel
__device__ __forceinline__ void bsplit(float x, u16& h, u16& l) {
  unsigned u = __float_as_uint(x);
  unsigned r = u + 0x7FFF + ((u >> 16) & 1);
  h = (u16)(r >> 16);
  float hf = __uint_as_float((unsigned)h << 16);
  float lof = x - hf;
  unsigned u2 = __float_as_uint(lof);
  unsigned r2 = u2 + 0x7FFF + ((u2 >> 16) & 1);
  l = (u16)(r2 >> 16);
}

// trunc split: x ~= hi + lo to ~2^-16 rel, cheap
__device__ __forceinline__ void tsplit(float x, u16& h, u16& l) {
  unsigned u = __float_as_uint(x);
  h = (u16)(u >> 16);
  float lof = x - __uint_as_float(u & 0xFFFF0000u);
  l = (u16)(__float_as_uint(lof) >> 16);
}

// exp(10*tanh(s)) with rcp instead of full divide (~1e-7 rel err)
__device__ __forceinline__ float exp10tanh(float s) {
  float ax = fabsf(s);
  float u = __expf(-2.0f * ax);                    // (0,1]
  float r = __builtin_amdgcn_rcpf(1.0f + u);
  float tt = fmaf(-2.0f * u, r, 1.0f);             // tanh(ax)
  tt = copysignf(tt, s);
  return __expf(10.0f * tt);
}

// ---------------- K0: transposed split weight planes ----------------
__global__ __launch_bounds__(256) void prep_weights(
    const float* __restrict__ Wq1, const float* __restrict__ Wq2,
    const float* __restrict__ Wql, const float* __restrict__ Wk,
    const float* __restrict__ Wv, u16* __restrict__ wcat_hi, u16* __restrict__ wcat_lo,
    u16* __restrict__ wkv_hi, u16* __restrict__ wkv_lo) {
  int t = threadIdx.x;
  if (blockIdx.x == 0) {
    for (int i = t; i < 128 * 384; i += 256) {
      int c = i / 384, k = i % 384;
      float v = (k < 128) ? Wq1[k * 128 + c]
                          : (k < 256) ? Wq2[(k - 128) * 128 + c] : Wql[(k - 256) * 128 + c];
      u16 h, l;
      bsplit(v, h, l);
      wcat_hi[i] = h;
      wcat_lo[i] = l;
    }
  } else {
    for (int i = t; i < 256 * 128; i += 256) {
      int c = i >> 7, k = i & 127;
      float v = (c < 128) ? Wk[k * 128 + c] : Wv[k * 128 + (c - 128)];
      u16 h, l;
      bsplit(v, h, l);
      wkv_hi[i] = h;
      wkv_lo[i] = l;
    }
  }
}

// ---------------- K1: k/v GEMM -> ekkP ([b][nch128][c256][8]) + nodesP ----------------
__global__ __launch_bounds__(256, 1) void kv_prep(
    const float* __restrict__ nodes, const u16* __restrict__ wkv_hi,
    const u16* __restrict__ wkv_lo, u16* __restrict__ ekkP_hi, u16* __restrict__ ekkP_lo,
    u16* __restrict__ nodesP_hi, u16* __restrict__ nodesP_lo) {
  __shared__ u16 a_hi[32 * 136], a_lo[32 * 136];
  __shared__ float kvbuf[32 * 264];
  const int t = threadIdx.x;
  const int xcd = blockIdx.x & 7, jj = blockIdx.x >> 3;
  const int b = xcd * 4 + (jj >> 5);
  const int n0 = (jj & 31) * 32;
  for (int i = t; i < 4096; i += 256) {
    int n = i >> 7, d = i & 127;
    float v = nodes[((long)(b * 1024 + n0 + n)) * 128 + d];
    u16 h, l;
    bsplit(v, h, l);
    a_hi[n * 136 + d] = h;
    a_lo[n * 136 + d] = l;
  }
  __syncthreads();
  const int lane = t & 63, w = t >> 6;
  const int lr = lane & 15, lg = lane >> 4;
  f32x4 acc0[2][4] = {}, acc1[2][4] = {};
#pragma unroll
  for (int ks = 0; ks < 4; ++ks) {
    us8 ah[2], al[2];
#pragma unroll
    for (int mt = 0; mt < 2; ++mt) {
      int ro = (lr + 16 * mt) * 136 + ks * 32 + lg * 8;
      ah[mt] = *(const us8*)&a_hi[ro];
      al[mt] = *(const us8*)&a_lo[ro];
    }
    us8 bh[4], bl[4];
#pragma unroll
    for (int cc = 0; cc < 4; ++cc) {
      long off = (long)((w * 4 + cc) * 16 + lr) * 128 + ks * 32 + lg * 8;
      bh[cc] = *(const us8*)&wkv_hi[off];
      bl[cc] = *(const us8*)&wkv_lo[off];
    }
#pragma unroll
    for (int mt = 0; mt < 2; ++mt)
#pragma unroll
      for (int cc = 0; cc < 4; ++cc) {
        acc0[mt][cc] = MFMA(asbf(ah[mt]), asbf(bh[cc]), acc0[mt][cc], 0, 0, 0);
        acc1[mt][cc] = MFMA(asbf(al[mt]), asbf(bh[cc]), acc1[mt][cc], 0, 0, 0);
        acc1[mt][cc] = MFMA(asbf(ah[mt]), asbf(bl[cc]), acc1[mt][cc], 0, 0, 0);
      }
  }
#pragma unroll
  for (int mt = 0; mt < 2; ++mt)
#pragma unroll
    for (int cc = 0; cc < 4; ++cc) {
      int c = (w * 4 + cc) * 16 + lr;
#pragma unroll
      for (int r = 0; r < 4; ++r)
        kvbuf[(lg * 4 + r + 16 * mt) * 264 + c] = acc0[mt][cc][r] + acc1[mt][cc][r];
    }
  __syncthreads();
#pragma unroll
  for (int jo = 0; jo < 4; ++jo) {
    int c = jo * 64 + (t & 63);
    int i4 = t >> 6;
    int kcol = (c < 128) ? c : (c - 128);
    us8 h8, l8;
#pragma unroll
    for (int jq = 0; jq < 8; ++jq) {
      int n = i4 * 8 + jq;
      float kv = kvbuf[n * 264 + kcol];
      float ek = __expf(kv);
      float val = (c < 128) ? ek * kvbuf[n * 264 + c + 128] : ek;
      u16 h, l;
      bsplit(val, h, l);
      h8[jq] = h;
      l8[jq] = l;
    }
    long o = (((long)b * 128 + (n0 >> 3) + i4) * 256 + c) * 8;
    *(us8*)&ekkP_hi[o] = h8;
    *(us8*)&ekkP_lo[o] = l8;
  }
  {
    int pl = t >> 7, r = t & 127;
    int dgrp = r >> 3, nb = r & 7;
    const u16* src = pl ? a_lo : a_hi;
    u16* dst = pl ? nodesP_lo : nodesP_hi;
#pragma unroll
    for (int i = 0; i < 4; ++i) {
      int n = nb + 8 * i;
      us8 v = *(const us8*)&src[n * 136 + dgrp * 8];
      *(us8*)&dst[(((long)(b * 16 + dgrp)) * 1024 + n0 + n) * 8] = v;
    }
  }
}

// ---------------- K2: q GEMM + sigmoid -> qsig f32 [32K][128] ----------------
__global__ __launch_bounds__(256) void qsig_prep(
    const float* __restrict__ q1m, const float* __restrict__ q2m,
    const float* __restrict__ lnm, const float* __restrict__ loadv,
    const float* __restrict__ leftv, const float* __restrict__ Wql,
    const u16* __restrict__ wcat_hi, const u16* __restrict__ wcat_lo,
    float* __restrict__ qsig) {
  const int t = threadIdx.x;
  const int lane = t & 63, w = t >> 6;
  const int lr = lane & 15, lg = lane >> 4;
  const long p0 = (long)blockIdx.x * 16;
  const long arow = p0 + lr;
  f32x4 qacc[2] = {};
#pragma unroll 2
  for (int s = 0; s < 12; ++s) {
    const float* __restrict__ src = (s < 4) ? q1m : (s < 8) ? q2m : lnm;
    long ao = arow * 128 + (s & 3) * 32 + lg * 8;
    float4 a0 = *(const float4*)&src[ao];
    float4 a1 = *(const float4*)&src[ao + 4];
    float av[8] = {a0.x, a0.y, a0.z, a0.w, a1.x, a1.y, a1.z, a1.w};
    us8 ah, al;
#pragma unroll
    for (int jq = 0; jq < 8; ++jq) {
      u16 hh, ll;
      tsplit(av[jq], hh, ll);
      ah[jq] = hh;
      al[jq] = ll;
    }
#pragma unroll
    for (int cf = 0; cf < 2; ++cf) {
      int c = w * 32 + cf * 16 + lr;
      us8 bh = *(const us8*)&wcat_hi[c * 384 + s * 32 + lg * 8];
      us8 bl = *(const us8*)&wcat_lo[c * 384 + s * 32 + lg * 8];
      qacc[cf] = MFMA(asbf(ah), asbf(bh), qacc[cf], 0, 0, 0);
      qacc[cf] = MFMA(asbf(al), asbf(bh), qacc[cf], 0, 0, 0);
      qacc[cf] = MFMA(asbf(ah), asbf(bl), qacc[cf], 0, 0, 0);
    }
  }
#pragma unroll
  for (int cf = 0; cf < 2; ++cf) {
    int c = w * 32 + cf * 16 + lr;
    float wl1 = Wql[128 * 128 + c], wl2 = Wql[129 * 128 + c];
#pragma unroll
    for (int r = 0; r < 4; ++r) {
      int row = lg * 4 + r;
      float qv = qacc[cf][r] + loadv[p0 + row] * wl1 + leftv[p0 + row] * wl2;
      qsig[(p0 + row) * 128 + c] = 1.0f / (1.0f + __expf(-qv));
    }
  }
}

// df ring element (held by reference -> static indexing, no scratch)
struct DFset {
  float4 d0, d1, f0, f1;
};

// ---------------- K3: fused bias + [num|den] GEMM (128r x 256c x K1024) + AFT epilogue ----------------
// 256 blocks (1/CU), 512 thr / 8 waves. lgkm-only barriers keep global loads in
// flight across stages; cdist/ninf prefetched 2 stages deep (DFset ring of 2).
__global__ __launch_bounds__(512, 2) void ndaft_gemm(
    const float* __restrict__ cdist, const float* __restrict__ ninf,
    const u16* __restrict__ ekkP_hi, const u16* __restrict__ ekkP_lo,
    const float* __restrict__ qsig, u16* __restrict__ aftP_hi,
    u16* __restrict__ aftP_lo, u16* __restrict__ bias16,
    const float* __restrict__ logs, const float* __restrict__ aal,
    const float* __restrict__ pal) {
  // A: [ptile8][pl2][oct4][136] u16 = 8704 ; B at 8704: hi[oct4][c256][8]=8192, lo +8192
  __shared__ u16 lds[25088];  // 50176 B
  const int t = threadIdx.x;
  const int lane = t & 63, w = t >> 6;
  const int lr = lane & 15, lg = lane >> 4;
  const int wr = w >> 2, wc = w & 3;
  const int xcd = blockIdx.x & 7, j = blockIdx.x >> 3;  // j 0..31
  const int b = xcd * 4 + (j & 3);
  const int pt = j >> 2;  // 0..7 (128 rows each)
  const long bp = (long)b * Pp + pt * 128;
  const float c1 = logs[0] * aal[0];
  const float c2 = logs[0] * pal[0];

  const int srow = t >> 2, soct = t & 3;  // A staging: 128 rows x 4 K-octs
  const long arow = bp + srow;
  const long tbase = (arow >> 4) * 32768;
  const int spr = srow & 15, sptile = srow >> 4;
  const long bsrc = (long)b * 128 * 2048;

  DFset dfA, dfB;
  us8 bst[4];
  us8 ebh, ebl;

  auto load_df = [&](DFset& df, int s) {
    long ao = arow * 1024 + s * 32 + soct * 8;
    df.d0 = *(const float4*)&cdist[ao];
    df.d1 = *(const float4*)&cdist[ao + 4];
    df.f0 = *(const float4*)&ninf[ao];
    df.f1 = *(const float4*)&ninf[ao + 4];
  };
  auto load_bst = [&](int s) {
    long sb = bsrc + (long)s * 8192;
#pragma unroll
    for (int i = 0; i < 2; ++i) {
      bst[i] = *(const us8*)&ekkP_hi[sb + (i * 512 + t) * 8];
      bst[i + 2] = *(const us8*)&ekkP_lo[sb + (i * 512 + t) * 8];
    }
  };
  auto compute_eb = [&](DFset& df, int s) {
    float dv[8] = {df.d0.x, df.d0.y, df.d0.z, df.d0.w, df.d1.x, df.d1.y, df.d1.z, df.d1.w};
    float nv[8] = {df.f0.x, df.f0.y, df.f0.z, df.f0.w, df.f1.x, df.f1.y, df.f1.z, df.f1.w};
    us8 q8;
#pragma unroll
    for (int jq = 0; jq < 8; ++jq) {
      float e = __expf(fmaf(-c1, dv[jq], nv[jq]));
      u16 h, l;
      tsplit(e, h, l);
      ebh[jq] = h;
      ebl[jq] = l;
      float x = fminf(fmaxf(c2 * dv[jq], 0.f), 15.999f);
      q8[jq] = (nv[jq] < -1e5f) ? (u16)0xFFFF : (u16)(x * 4096.f + 0.5f);
    }
    *(us8*)&bias16[tbase + ((s * 4 + soct) * 16 + spr) * 8] = q8;
  };
  auto write_lds = [&]() {
    *(us8*)&lds[((sptile * 2 + 0) * 4 + soct) * 136 + spr * 8] = ebh;
    *(us8*)&lds[((sptile * 2 + 1) * 4 + soct) * 136 + spr * 8] = ebl;
#pragma unroll
    for (int i = 0; i < 2; ++i) {
      *(us8*)&lds[8704 + (i * 512 + t) * 8] = bst[i];
      *(us8*)&lds[8704 + 8192 + (i * 512 + t) * 8] = bst[i + 2];
    }
  };

  f32x4 acc[4][4] = {};

  // prologue: df(0)->A, df(1)->B, bst(0); eb(0) from A
  load_df(dfA, 0);
  load_df(dfB, 1);
  load_bst(0);
  compute_eb(dfA, 0);

  // one stage; refill = df set to load s+2 into; consume = df set holding s+1
  auto stage = [&](int s, DFset& refill, DFset& consume) {
    // bar1: all waves' ds_reads of stage s-1 done (lgkm only; vmcnt stays in flight)
    asm volatile("s_waitcnt lgkmcnt(0)" ::: "memory");
    __builtin_amdgcn_s_barrier();
    __builtin_amdgcn_sched_barrier(0);
    write_lds();  // A(s) from eb regs, B(s) from bst (waits its vmcnt via dep)
    asm volatile("s_waitcnt lgkmcnt(0)" ::: "memory");
    __builtin_amdgcn_s_barrier();
    __builtin_amdgcn_sched_barrier(0);
    if (s < 31) load_bst(s + 1);          // global->reg, in flight over next barrier
    if (s < 30) load_df(refill, s + 2);   // HBM, 2 stages deep
    if (s < 31) compute_eb(consume, s + 1);
    us8 ah[4], al[4];
#pragma unroll
    for (int mt = 0; mt < 4; ++mt) {
      int ptl = wr * 4 + mt;
      ah[mt] = *(const us8*)&lds[((ptl * 2 + 0) * 4 + lg) * 136 + lr * 8];
      al[mt] = *(const us8*)&lds[((ptl * 2 + 1) * 4 + lg) * 136 + lr * 8];
    }
#pragma unroll
    for (int ct = 0; ct < 4; ++ct) {
      int c = (ct < 2) ? (wc * 32 + ct * 16 + lr) : (96 + wc * 32 + ct * 16 + lr);
      us8 bh = *(const us8*)&lds[8704 + lg * 2048 + c * 8];
      us8 bl = *(const us8*)&lds[8704 + 8192 + lg * 2048 + c * 8];
#pragma unroll
      for (int mt = 0; mt < 4; ++mt) {
        acc[mt][ct] = MFMA(asbf(ah[mt]), asbf(bh), acc[mt][ct], 0, 0, 0);
        acc[mt][ct] = MFMA(asbf(al[mt]), asbf(bh), acc[mt][ct], 0, 0, 0);
        acc[mt][ct] = MFMA(asbf(ah[mt]), asbf(bl), acc[mt][ct], 0, 0, 0);
      }
    }
  };

#pragma unroll 1
  for (int s2 = 0; s2 < 32; s2 += 2) {
    stage(s2, dfA, dfB);       // refill A with df(s2+2), consume B (df(s2+1))
    stage(s2 + 1, dfB, dfA);   // refill B with df(s2+3), consume A (df(s2+2))
  }

  // epilogue: aft = sig * num * rcp(den+eps) -> split bf16, packed aftP
#pragma unroll
  for (int mt = 0; mt < 4; ++mt)
#pragma unroll
    for (int ct = 0; ct < 2; ++ct) {
      int cn = wc * 32 + ct * 16 + lr;
      int nc = cn >> 3, jq = cn & 7;
#pragma unroll
      for (int r = 0; r < 4; ++r) {
        long gr = bp + wr * 64 + mt * 16 + lg * 4 + r;
        float sig = qsig[gr * 128 + cn];
        float aftv = sig * acc[mt][ct][r] * __builtin_amdgcn_rcpf(acc[mt][ct + 2][r] + 1e-20f);
        u16 h, l;
        bsplit(aftv, h, l);
        long idx = (gr >> 4) * 2048 + (nc * 16 + (gr & 15)) * 8 + jq;
        aftP_hi[idx] = h;
        aftP_lo[idx] = l;
      }
    }
}

// ---------------- K4: score GEMM (transposed) + tanh-clip softmax ----------------
__global__ __launch_bounds__(256, 4) void score_softmax(
    const u16* bias16, const u16* __restrict__ aftP_hi, const u16* __restrict__ aftP_lo,
    const u16* __restrict__ nodesP_hi, const u16* __restrict__ nodesP_lo,
    float* out) {
  __shared__ float psum[16 * 4];
  __shared__ float invb[16];
  const int t = threadIdx.x;
  const int lane = t & 63, w = t >> 6;  // w = n-quarter
  const int lr = lane & 15, lg = lane >> 4;
  const int xcd = blockIdx.x & 7, j = blockIdx.x >> 3;  // j 0..255
  const int b = xcd * 4 + (j >> 6);
  const int tl = j & 63;
  const int p0 = tl * 16;
  const long bp = (long)b * Pp + p0;
  const int tile = b * 64 + tl;

  f32x4 sacc[16] = {};
#pragma unroll
  for (int ks = 0; ks < 4; ++ks) {
    long aoff = (long)tile * 2048 + ((long)((ks * 4 + lg) * 16 + lr)) * 8;
    us8 ah = *(const us8*)&aftP_hi[aoff];
    us8 al = *(const us8*)&aftP_lo[aoff];
    long nb = ((long)(b * 16 + ks * 4 + lg)) * 1024;
    auto bld = [&](int cf, us8& bh, us8& bl) {
      long o = (nb + w * 256 + cf * 16 + lr) * 8;
      bh = *(const us8*)&nodesP_hi[o];
      bl = *(const us8*)&nodesP_lo[o];
    };
    us8 bh0, bl0, bh1, bl1;
    bld(0, bh0, bl0);
    bld(1, bh1, bl1);
#pragma unroll
    for (int cf = 0; cf < 16; ++cf) {
      us8 nh = bh1, nl = bl1;
      if (cf < 14) bld(cf + 2, nh, nl);  // issue 2 iterations ahead
      sacc[cf] = MFMA(asbf(bh0), asbf(ah), sacc[cf], 0, 0, 0);
      sacc[cf] = MFMA(asbf(bl0), asbf(ah), sacc[cf], 0, 0, 0);
      sacc[cf] = MFMA(asbf(bh0), asbf(al), sacc[cf], 0, 0, 0);
      bh0 = bh1; bl0 = bl1; bh1 = nh; bl1 = nl;
    }
  }

  const long btile = (long)tile * 32768;
  float rs = 0.f;
#pragma unroll
  for (int cf = 0; cf < 16; ++cf) {
    int nc = w * 32 + cf * 2 + (lg >> 1);
    int j0 = (lg & 1) * 4;
    us4 q4 = *(const us4*)&bias16[btile + (nc * 16 + lr) * 8 + j0];
#pragma unroll
    for (int r = 0; r < 4; ++r) {
      u16 qv = q4[r];
      float sv = fmaf(sacc[cf][r], INV_SQRT_E, (float)qv * -2.44140625e-4f);
      float e = exp10tanh(sv);
      e = (qv == (u16)0xFFFF) ? 0.f : e;
      sacc[cf][r] = e;
      rs += e;
    }
  }
  rs += __shfl_xor(rs, 16);
  rs += __shfl_xor(rs, 32);
  if (lane < 16) psum[lr * 4 + w] = rs;
  __syncthreads();
  if (t < 16)
    invb[t] = 1.0f / (psum[t * 4] + psum[t * 4 + 1] + psum[t * 4 + 2] + psum[t * 4 + 3]);
  __syncthreads();

  const float inv = invb[lr];
  const long ro = (bp + lr) * (long)Nn + w * 256;
#pragma unroll
  for (int cf = 0; cf < 16; ++cf) {
    float4 v;
    v.x = sacc[cf][0] * inv;
    v.y = sacc[cf][1] * inv;
    v.z = sacc[cf][2] * inv;
    v.w = sacc[cf][3] * inv;
    *(float4*)&out[ro + cf * 16 + lg * 4] = v;
  }
}

extern "C" void kernel_launch(void* const* d_in, const int* in_sizes, int n_in,
                              void* d_out, int out_size, void* d_ws, size_t ws_size,
                              hipStream_t stream) {
  const float* nodes = (const float*)d_in[0];
  const float* q1m = (const float*)d_in[1];
  const float* q2m = (const float*)d_in[2];
  const float* lnm = (const float*)d_in[3];
  const float* loadv = (const float*)d_in[4];
  const float* leftv = (const float*)d_in[5];
  const float* cdist = (const float*)d_in[6];
  const float* logs = (const float*)d_in[7];
  const float* ninf = (const float*)d_in[8];
  const float* Wq1 = (const float*)d_in[9];
  const float* Wq2 = (const float*)d_in[10];
  const float* Wql = (const float*)d_in[11];
  const float* Wk = (const float*)d_in[12];
  const float* Wv = (const float*)d_in[13];
  const float* aalpha = (const float*)d_in[14];
  const float* palpha = (const float*)d_in[15];

  char* ws = (char*)d_ws;
  u16* ekkP_hi = (u16*)ws;                      // 16 MB
  u16* ekkP_lo = (u16*)(ws + (16ul << 20));     // 16 MB
  u16* nodesP_hi = (u16*)(ws + (32ul << 20));   // 8 MB
  u16* nodesP_lo = (u16*)(ws + (40ul << 20));   // 8 MB
  float* qsig = (float*)(ws + (48ul << 20));    // 16 MB
  u16* aftP_hi = (u16*)(ws + (64ul << 20));     // 8 MB
  u16* aftP_lo = (u16*)(ws + (72ul << 20));     // 8 MB
  u16* wcat_hi = (u16*)(ws + (80ul << 20));
  u16* wcat_lo = wcat_hi + 128 * 384;
  u16* wkv_hi = wcat_lo + 128 * 384;
  u16* wkv_lo = wkv_hi + 256 * 128;
  u16* bias16 = (u16*)d_out;  // first 32KB of each 64KB out-tile; read-then-overwritten

  prep_weights<<<2, 256, 0, stream>>>(Wq1, Wq2, Wql, Wk, Wv, wcat_hi, wcat_lo, wkv_hi, wkv_lo);
  kv_prep<<<Bb * Nn / 32, 256, 0, stream>>>(nodes, wkv_hi, wkv_lo, ekkP_hi, ekkP_lo,
                                            nodesP_hi, nodesP_lo);
  qsig_prep<<<2048, 256, 0, stream>>>(q1m, q2m, lnm, loadv, leftv, Wql, wcat_hi, wcat_lo,
                                      qsig);
  ndaft_gemm<<<256, 512, 0, stream>>>(cdist, ninf, ekkP_hi, ekkP_lo, qsig, aftP_hi,
                                      aftP_lo, bias16, logs, aalpha, palpha);
  score_softmax<<<Bb * Pp / 16, 256, 0, stream>>>(
      bias16, aftP_hi, aftP_lo, nodesP_hi, nodesP_lo, (float*)d_out);
}